// Round 1
// baseline (1661.165 us; speedup 1.0000x reference)
//
#include <hip/hip_runtime.h>
#include <hip/hip_bf16.h>
#include <math.h>

#define NN 10000
#define NE 160000

// ---------------- CSR build (dst-sorted edge permutation) ----------------
__global__ void count_kernel(const int* __restrict__ dst, int* __restrict__ counts, int E) {
  int e = blockIdx.x * blockDim.x + threadIdx.x;
  if (e < E) atomicAdd(&counts[dst[e]], 1);
}

__global__ __launch_bounds__(1024) void scan_kernel(const int* __restrict__ counts,
                                                    int* __restrict__ row_ptr,
                                                    int* __restrict__ cursor, int N) {
  __shared__ int sums[1024];
  int t = threadIdx.x;
  const int CH = (N + 1023) >> 10;
  int base = t * CH;
  int s = 0;
  for (int i = 0; i < CH; ++i) { int idx = base + i; if (idx < N) s += counts[idx]; }
  sums[t] = s;
  __syncthreads();
  for (int off = 1; off < 1024; off <<= 1) {
    int v = 0;
    if (t >= off) v = sums[t - off];
    __syncthreads();
    if (t >= off) sums[t] += v;
    __syncthreads();
  }
  int run = (t == 0) ? 0 : sums[t - 1];
  for (int i = 0; i < CH; ++i) {
    int idx = base + i;
    if (idx < N) { row_ptr[idx] = run; cursor[idx] = run; run += counts[idx]; }
  }
  if (t == 0) row_ptr[N] = sums[1023];
}

__global__ void scatter_kernel(const int* __restrict__ dst, int* __restrict__ cursor,
                               int* __restrict__ eperm, int E) {
  int e = blockIdx.x * blockDim.x + threadIdx.x;
  if (e < E) {
    int pos = atomicAdd(&cursor[dst[e]], 1);
    eperm[pos] = e;
  }
}

// ---------------- fp32 tiled GEMM: C[M,N] = A[M,K] (+A2) @ B[K,N] ----------------
template<bool ADD2>
__global__ __launch_bounds__(256) void gemm_kernel(const float* __restrict__ A,
                                                   const float* __restrict__ A2,
                                                   const float* __restrict__ B,
                                                   float* __restrict__ C,
                                                   int M, int N, int K) {
  __shared__ float As[16][64];
  __shared__ float Bs[16][64];
  int tid = threadIdx.x;
  int tx = tid & 15;   // n dir
  int ty = tid >> 4;   // m dir
  int m0 = blockIdx.y * 64;
  int n0 = blockIdx.x * 64;

  float acc[4][4] = {};

  for (int k0 = 0; k0 < K; k0 += 16) {
#pragma unroll
    for (int i = 0; i < 4; ++i) {
      int j = tid * 4 + i;
      int r = j >> 4, c = j & 15;            // r: m within tile, c: k within tile
      int gm = m0 + r, gk = k0 + c;
      float v = 0.f;
      if (gm < M && gk < K) {
        v = A[(size_t)gm * K + gk];
        if (ADD2) v += A2[(size_t)gm * K + gk];
      }
      As[c][r] = v;
    }
#pragma unroll
    for (int i = 0; i < 4; ++i) {
      int j = tid * 4 + i;
      int r = j >> 6, c = j & 63;            // r: k within tile, c: n within tile
      int gk = k0 + r, gn = n0 + c;
      Bs[r][c] = (gk < K && gn < N) ? B[(size_t)gk * N + gn] : 0.f;
    }
    __syncthreads();
#pragma unroll
    for (int k = 0; k < 16; ++k) {
      float av[4], bv[4];
#pragma unroll
      for (int i = 0; i < 4; ++i) av[i] = As[k][ty * 4 + i];
#pragma unroll
      for (int j = 0; j < 4; ++j) bv[j] = Bs[k][tx * 4 + j];
#pragma unroll
      for (int i = 0; i < 4; ++i)
#pragma unroll
        for (int j = 0; j < 4; ++j) acc[i][j] += av[i] * bv[j];
    }
    __syncthreads();
  }
#pragma unroll
  for (int i = 0; i < 4; ++i) {
    int gm = m0 + ty * 4 + i;
    if (gm >= M) continue;
#pragma unroll
    for (int j = 0; j < 4; ++j) {
      int gn = n0 + tx * 4 + j;
      if (gn < N) C[(size_t)gm * N + gn] = acc[i][j];
    }
  }
}

// ---------------- attention source/dst scores: att[n,h] = sum_f Wh[n,h,f]*a[h,(side)f] ----------------
template<int H, int F>
__global__ void att_kernel(const float* __restrict__ Wh, const float* __restrict__ a,
                           float* __restrict__ att_s, float* __restrict__ att_d, int N) {
  int n = blockIdx.x;
  int h = threadIdx.x >> 6;
  int lane = threadIdx.x & 63;
  const float* w = Wh + ((size_t)n * H + h) * F;
  const float* as = a + (size_t)h * 2 * F;
  const float* ad = as + F;
  float ss = 0.f, sd = 0.f;
  for (int f = lane; f < F; f += 64) {
    float v = w[f];
    ss += v * as[f];
    sd += v * ad[f];
  }
#pragma unroll
  for (int off = 32; off > 0; off >>= 1) {
    ss += __shfl_down(ss, off);
    sd += __shfl_down(sd, off);
  }
  if (lane == 0) {
    att_s[n * H + h] = ss;
    att_d[n * H + h] = sd;
  }
}

// ---------------- edge phase ----------------
__global__ void edge_logit_max(const int* __restrict__ src, const int* __restrict__ dst,
                               const float* __restrict__ att_s, const float* __restrict__ att_d,
                               float* __restrict__ ebuf, unsigned* __restrict__ mkey,
                               int E, int H) {
  int i = blockIdx.x * blockDim.x + threadIdx.x;
  if (i >= E * H) return;
  int e = i / H, h = i - e * H;
  int s = src[e], d = dst[e];
  float x = att_s[s * H + h] + att_d[d * H + h];
  float l = x >= 0.f ? x : 0.2f * x;
  ebuf[i] = l;
  unsigned b = __float_as_uint(l);
  unsigned key = (b & 0x80000000u) ? ~b : (b | 0x80000000u);  // order-preserving encode
  atomicMax(&mkey[d * H + h], key);
}

__global__ void edge_exp_sum(const int* __restrict__ dst, const unsigned* __restrict__ mkey,
                             float* __restrict__ ebuf, float* __restrict__ denom,
                             int E, int H) {
  int i = blockIdx.x * blockDim.x + threadIdx.x;
  if (i >= E * H) return;
  int e = i / H, h = i - e * H;
  int d = dst[e];
  unsigned key = mkey[d * H + h];
  float m;
  if (key == 0u) m = -INFINITY;
  else {
    unsigned b = (key & 0x80000000u) ? (key & 0x7FFFFFFFu) : ~key;
    m = __uint_as_float(b);
  }
  float ev = expf(ebuf[i] - m);
  ebuf[i] = ev;
  atomicAdd(&denom[d * H + h], ev);
}

__global__ void edge_coef(const int* __restrict__ dst, float* __restrict__ ebuf,
                          const float* __restrict__ denom, int E, int H) {
  int i = blockIdx.x * blockDim.x + threadIdx.x;
  if (i >= E * H) return;
  int e = i / H, h = i - e * H;
  int d = dst[e];
  ebuf[i] = ebuf[i] / (denom[d * H + h] + 1e-16f);
}

// ---------------- aggregate: out[n] = sum_{e: dst=n} coef[e,h] * Wh[src[e],h,f] ----------------
template<int H, int F, bool MEAN, bool ELU>
__global__ __launch_bounds__(256) void aggregate_kernel(const int* __restrict__ row_ptr,
                                                        const int* __restrict__ eperm,
                                                        const int* __restrict__ src,
                                                        const float* __restrict__ coef,
                                                        const float* __restrict__ Wh,
                                                        float* __restrict__ out, int N) {
  constexpr int HF = H * F;
  constexpr int T = 256;
  constexpr int PER = (HF + T - 1) / T;
  int n = blockIdx.x;
  int t = threadIdx.x;
  float acc[PER];
  int hL[PER];
#pragma unroll
  for (int p = 0; p < PER; ++p) {
    acc[p] = 0.f;
    int idx = t + p * T;
    hL[p] = (idx < HF) ? (idx / F) : 0;
  }
  int beg = row_ptr[n], end = row_ptr[n + 1];
  for (int k = beg; k < end; ++k) {
    int e = eperm[k];
    int s = src[e];
    const float* w = Wh + (size_t)s * HF;
    const float* c = coef + (size_t)e * H;
#pragma unroll
    for (int p = 0; p < PER; ++p) {
      int idx = t + p * T;
      if (HF % T == 0 || idx < HF) acc[p] += c[hL[p]] * w[idx];
    }
  }
  if constexpr (!MEAN) {
#pragma unroll
    for (int p = 0; p < PER; ++p) {
      int idx = t + p * T;
      if (HF % T == 0 || idx < HF) {
        float v = acc[p];
        if (ELU) v = v > 0.f ? v : expm1f(v);
        out[(size_t)n * HF + idx] = v;
      }
    }
  } else {
    __shared__ float buf[HF];
#pragma unroll
    for (int p = 0; p < PER; ++p) {
      int idx = t + p * T;
      if (idx < HF) buf[idx] = acc[p];
    }
    __syncthreads();
    for (int f = t; f < F; f += T) {
      float s = 0.f;
#pragma unroll
      for (int h = 0; h < H; ++h) s += buf[h * F + f];
      out[(size_t)n * F + f] = s * (1.0f / H);
    }
  }
}

extern "C" void kernel_launch(void* const* d_in, const int* in_sizes, int n_in,
                              void* d_out, int out_size, void* d_ws, size_t ws_size,
                              hipStream_t stream) {
  const float* x  = (const float*)d_in[0];
  const int* eidx = (const int*)d_in[1];
  const float* W1 = (const float*)d_in[2];
  const float* a1 = (const float*)d_in[3];
  const float* W2 = (const float*)d_in[4];
  const float* a2 = (const float*)d_in[5];
  const float* W3 = (const float*)d_in[6];
  const float* a3 = (const float*)d_in[7];
  float* out = (float*)d_out;

  const int N = NN, E = NE;
  const int* src = eidx;
  const int* dst = eidx + E;

  char* ws = (char*)d_ws;
  size_t off = 0;
  auto alloc = [&](size_t bytes) -> void* {
    void* p = ws + off;
    off += (bytes + 255) & ~(size_t)255;
    return p;
  };
  float* Wh      = (float*)alloc((size_t)N * 1024 * 4);
  float* h1      = (float*)alloc((size_t)N * 1024 * 4);
  float* h2      = (float*)alloc((size_t)N * 1024 * 4);
  float* atts    = (float*)alloc((size_t)N * 6 * 4);
  float* attd    = (float*)alloc((size_t)N * 6 * 4);
  float* ebuf    = (float*)alloc((size_t)E * 6 * 4);
  unsigned* mkey = (unsigned*)alloc((size_t)N * 6 * 4);
  float* denom   = (float*)alloc((size_t)N * 6 * 4);
  int* counts    = (int*)alloc((size_t)N * 4);
  int* row_ptr   = (int*)alloc((size_t)(N + 1) * 4);
  int* cursor    = (int*)alloc((size_t)N * 4);
  int* eperm     = (int*)alloc((size_t)E * 4);

  // ---- CSR by dst (rebuilt every call; deterministic inputs) ----
  hipMemsetAsync(counts, 0, (size_t)N * 4, stream);
  count_kernel<<<(E + 255) / 256, 256, 0, stream>>>(dst, counts, E);
  scan_kernel<<<1, 1024, 0, stream>>>(counts, row_ptr, cursor, N);
  scatter_kernel<<<(E + 255) / 256, 256, 0, stream>>>(dst, cursor, eperm, E);

  auto run_edges = [&](int H, const float* as_, const float* ad_) {
    int total = E * H;
    hipMemsetAsync(mkey, 0, (size_t)N * H * 4, stream);
    hipMemsetAsync(denom, 0, (size_t)N * H * 4, stream);
    edge_logit_max<<<(total + 255) / 256, 256, 0, stream>>>(src, dst, as_, ad_, ebuf, mkey, E, H);
    edge_exp_sum<<<(total + 255) / 256, 256, 0, stream>>>(dst, mkey, ebuf, denom, E, H);
    edge_coef<<<(total + 255) / 256, 256, 0, stream>>>(dst, ebuf, denom, E, H);
  };

  int mblocks = (N + 63) / 64;

  // ---- layer 1: x[10000,50] @ W1[50,1024] ----
  gemm_kernel<false><<<dim3(1024 / 64, mblocks), 256, 0, stream>>>(x, nullptr, W1, Wh, N, 1024, 50);
  att_kernel<4, 256><<<N, 256, 0, stream>>>(Wh, a1, atts, attd, N);
  run_edges(4, atts, attd);
  aggregate_kernel<4, 256, false, true><<<N, 256, 0, stream>>>(row_ptr, eperm, src, ebuf, Wh, h1, N);

  // ---- layer 2: h1 @ W2[1024,1024] ----
  gemm_kernel<false><<<dim3(1024 / 64, mblocks), 256, 0, stream>>>(h1, nullptr, W2, Wh, N, 1024, 1024);
  att_kernel<4, 256><<<N, 256, 0, stream>>>(Wh, a2, atts, attd, N);
  run_edges(4, atts, attd);
  aggregate_kernel<4, 256, false, true><<<N, 256, 0, stream>>>(row_ptr, eperm, src, ebuf, Wh, h2, N);

  // ---- layer 3: (h1+h2) @ W3[1024,726], mean over 6 heads ----
  gemm_kernel<true><<<dim3((726 + 63) / 64, mblocks), 256, 0, stream>>>(h1, h2, W3, Wh, N, 726, 1024);
  att_kernel<6, 121><<<N, 384, 0, stream>>>(Wh, a3, atts, attd, N);
  run_edges(6, atts, attd);
  aggregate_kernel<6, 121, true, false><<<N, 256, 0, stream>>>(row_ptr, eperm, src, ebuf, Wh, out, N);
}

// Round 2
// 661.053 us; speedup vs baseline: 2.5129x; 2.5129x over previous
//
#include <hip/hip_runtime.h>
#include <hip/hip_bf16.h>
#include <math.h>

#define NN 10000
#define NE 160000

typedef __attribute__((ext_vector_type(8))) short bf16x8;
typedef __attribute__((ext_vector_type(4))) short bf16x4;
typedef __attribute__((ext_vector_type(4))) float f32x4;

static __device__ __forceinline__ unsigned short f2bf(float f) {
  unsigned u = __builtin_bit_cast(unsigned, f);
  unsigned r = u + 0x7fffu + ((u >> 16) & 1u);   // RNE
  return (unsigned short)(r >> 16);
}
static __device__ __forceinline__ float bf2f(unsigned short s) {
  return __builtin_bit_cast(float, (unsigned)s << 16);
}

// ---------------- CSR build (dst-sorted edge permutation) ----------------
__global__ void count_kernel(const int* __restrict__ dst, int* __restrict__ counts, int E) {
  int e = blockIdx.x * blockDim.x + threadIdx.x;
  if (e < E) atomicAdd(&counts[dst[e]], 1);
}

__global__ __launch_bounds__(1024) void scan_kernel(const int* __restrict__ counts,
                                                    int* __restrict__ row_ptr,
                                                    int* __restrict__ cursor, int N) {
  __shared__ int sums[1024];
  int t = threadIdx.x;
  const int CH = (N + 1023) >> 10;
  int base = t * CH;
  int s = 0;
  for (int i = 0; i < CH; ++i) { int idx = base + i; if (idx < N) s += counts[idx]; }
  sums[t] = s;
  __syncthreads();
  for (int off = 1; off < 1024; off <<= 1) {
    int v = 0;
    if (t >= off) v = sums[t - off];
    __syncthreads();
    if (t >= off) sums[t] += v;
    __syncthreads();
  }
  int run = (t == 0) ? 0 : sums[t - 1];
  for (int i = 0; i < CH; ++i) {
    int idx = base + i;
    if (idx < N) { row_ptr[idx] = run; cursor[idx] = run; run += counts[idx]; }
  }
  if (t == 0) row_ptr[N] = sums[1023];
}

__global__ void scatter_kernel(const int* __restrict__ dst, int* __restrict__ cursor,
                               int* __restrict__ eperm, int E) {
  int e = blockIdx.x * blockDim.x + threadIdx.x;
  if (e < E) {
    int pos = atomicAdd(&cursor[dst[e]], 1);
    eperm[pos] = e;
  }
}

// ---------------- weight split+transpose: W[K][N] fp32 -> Wt_hi/lo [Npad][KP] bf16 ----------------
__global__ void split_w_kernel(const float* __restrict__ W, short* __restrict__ hi,
                               short* __restrict__ lo, int K, int N, int Npad, int KP) {
  int idx = blockIdx.x * blockDim.x + threadIdx.x;
  if (idx >= Npad * KP) return;
  int n = idx / KP, k = idx - n * KP;
  float v = (n < N && k < K) ? W[(size_t)k * N + n] : 0.f;
  unsigned short h = f2bf(v);
  hi[idx] = (short)h;
  lo[idx] = (short)f2bf(v - bf2f(h));
}

// ---------------- split-bf16 MFMA GEMM: C[M,Nc] = (A (+A2)) @ B, B pre-split [Npad][KP] ----------------
// 128x128 tile, BK=32, 4 waves (2x2), each wave 64x64 via 4x4 16x16x32 MFMA tiles, 3 products each.
template<bool ADD2, bool VEC>
__global__ __launch_bounds__(256) void gemm_mfma(const float* __restrict__ A,
                                                 const float* __restrict__ A2,
                                                 const short* __restrict__ Bhi,
                                                 const short* __restrict__ Blo,
                                                 float* __restrict__ C,
                                                 int M, int Nc, int K, int KP) {
  __shared__ short As_hi[128 * 40];
  __shared__ short As_lo[128 * 40];
  __shared__ short Bs_hi[128 * 40];
  __shared__ short Bs_lo[128 * 40];

  const int t = threadIdx.x;
  const int lane = t & 63;
  const int wid = t >> 6;
  const int wr = wid >> 1;      // wave row (0..1)
  const int wc = wid & 1;       // wave col (0..1)
  const int row_in = lane & 15;
  const int kgrp = lane >> 4;

  const int m0 = blockIdx.y * 128;
  const int n0 = blockIdx.x * 128;

  f32x4 acc[4][4];
#pragma unroll
  for (int i = 0; i < 4; ++i)
#pragma unroll
    for (int j = 0; j < 4; ++j) acc[i][j] = (f32x4){0.f, 0.f, 0.f, 0.f};

  for (int k0 = 0; k0 < KP; k0 += 32) {
    if (k0) __syncthreads();
    // ---- stage A: [128 rows][32 k] fp32 -> split bf16 LDS ----
#pragma unroll
    for (int i = 0; i < 4; ++i) {
      int lin = (i * 256 + t) * 4;
      int row = lin >> 5;            // 0..127
      int k = lin & 31;              // multiple of 4
      int gm = m0 + row;
      if (gm >= M) gm = M - 1;       // clamp (C store masked)
      float v[4];
      if (VEC) {
        f32x4 va = *(const f32x4*)&A[(size_t)gm * K + k0 + k];
        if (ADD2) {
          f32x4 vb = *(const f32x4*)&A2[(size_t)gm * K + k0 + k];
          va += vb;
        }
        v[0] = va.x; v[1] = va.y; v[2] = va.z; v[3] = va.w;
      } else {
#pragma unroll
        for (int e = 0; e < 4; ++e) {
          int gk = k0 + k + e;
          float x = (gk < K) ? A[(size_t)gm * K + gk] : 0.f;
          if (ADD2 && gk < K) x += A2[(size_t)gm * K + gk];
          v[e] = x;
        }
      }
      short h4[4], l4[4];
#pragma unroll
      for (int e = 0; e < 4; ++e) {
        unsigned short h = f2bf(v[e]);
        h4[e] = (short)h;
        l4[e] = (short)f2bf(v[e] - bf2f(h));
      }
      *(bf16x4*)&As_hi[row * 40 + k] = (bf16x4){h4[0], h4[1], h4[2], h4[3]};
      *(bf16x4*)&As_lo[row * 40 + k] = (bf16x4){l4[0], l4[1], l4[2], l4[3]};
    }
    // ---- stage B: [128 cols][32 k] from pre-split global [Npad][KP] ----
#pragma unroll
    for (int r = 0; r < 2; ++r) {
      int lin = (r * 256 + t) * 8;
      int col = lin >> 5;            // 0..127
      int k = lin & 31;              // multiple of 8
      size_t g = (size_t)(n0 + col) * KP + k0 + k;
      *(bf16x8*)&Bs_hi[col * 40 + k] = *(const bf16x8*)&Bhi[g];
      *(bf16x8*)&Bs_lo[col * 40 + k] = *(const bf16x8*)&Blo[g];
    }
    __syncthreads();

    // ---- fragments + MFMA ----
    bf16x8 ah[4], al[4], bh[4], bl[4];
#pragma unroll
    for (int mi = 0; mi < 4; ++mi) {
      int r = (wr * 64 + mi * 16 + row_in) * 40 + kgrp * 8;
      ah[mi] = *(const bf16x8*)&As_hi[r];
      al[mi] = *(const bf16x8*)&As_lo[r];
    }
#pragma unroll
    for (int ni = 0; ni < 4; ++ni) {
      int r = (wc * 64 + ni * 16 + row_in) * 40 + kgrp * 8;
      bh[ni] = *(const bf16x8*)&Bs_hi[r];
      bl[ni] = *(const bf16x8*)&Bs_lo[r];
    }
#pragma unroll
    for (int mi = 0; mi < 4; ++mi)
#pragma unroll
      for (int ni = 0; ni < 4; ++ni) {
        acc[mi][ni] = __builtin_amdgcn_mfma_f32_16x16x32_bf16(ah[mi], bh[ni], acc[mi][ni], 0, 0, 0);
        acc[mi][ni] = __builtin_amdgcn_mfma_f32_16x16x32_bf16(al[mi], bh[ni], acc[mi][ni], 0, 0, 0);
        acc[mi][ni] = __builtin_amdgcn_mfma_f32_16x16x32_bf16(ah[mi], bl[ni], acc[mi][ni], 0, 0, 0);
      }
  }

  // ---- epilogue: D layout col=lane&15, row=(lane>>4)*4+j ----
#pragma unroll
  for (int mi = 0; mi < 4; ++mi) {
#pragma unroll
    for (int ni = 0; ni < 4; ++ni) {
      int gn = n0 + wc * 64 + ni * 16 + row_in;
      if (gn >= Nc) continue;
#pragma unroll
      for (int j = 0; j < 4; ++j) {
        int gm = m0 + wr * 64 + mi * 16 + kgrp * 4 + j;
        if (gm < M) C[(size_t)gm * Nc + gn] = acc[mi][ni][j];
      }
    }
  }
}

// ---------------- attention source/dst scores ----------------
template<int H, int F>
__global__ void att_kernel(const float* __restrict__ Wh, const float* __restrict__ a,
                           float* __restrict__ att_s, float* __restrict__ att_d, int N) {
  int n = blockIdx.x;
  int h = threadIdx.x >> 6;
  int lane = threadIdx.x & 63;
  const float* w = Wh + ((size_t)n * H + h) * F;
  const float* as = a + (size_t)h * 2 * F;
  const float* ad = as + F;
  float ss = 0.f, sd = 0.f;
  for (int f = lane; f < F; f += 64) {
    float v = w[f];
    ss += v * as[f];
    sd += v * ad[f];
  }
#pragma unroll
  for (int off = 32; off > 0; off >>= 1) {
    ss += __shfl_down(ss, off);
    sd += __shfl_down(sd, off);
  }
  if (lane == 0) {
    att_s[n * H + h] = ss;
    att_d[n * H + h] = sd;
  }
}

// ---------------- edge phase ----------------
__global__ void edge_logit_max(const int* __restrict__ src, const int* __restrict__ dst,
                               const float* __restrict__ att_s, const float* __restrict__ att_d,
                               float* __restrict__ ebuf, unsigned* __restrict__ mkey,
                               int E, int H) {
  int i = blockIdx.x * blockDim.x + threadIdx.x;
  if (i >= E * H) return;
  int e = i / H, h = i - e * H;
  int s = src[e], d = dst[e];
  float x = att_s[s * H + h] + att_d[d * H + h];
  float l = x >= 0.f ? x : 0.2f * x;
  ebuf[i] = l;
  unsigned b = __float_as_uint(l);
  unsigned key = (b & 0x80000000u) ? ~b : (b | 0x80000000u);
  atomicMax(&mkey[d * H + h], key);
}

__global__ void edge_exp_sum(const int* __restrict__ dst, const unsigned* __restrict__ mkey,
                             float* __restrict__ ebuf, float* __restrict__ denom,
                             int E, int H) {
  int i = blockIdx.x * blockDim.x + threadIdx.x;
  if (i >= E * H) return;
  int e = i / H, h = i - e * H;
  int d = dst[e];
  unsigned key = mkey[d * H + h];
  float m;
  if (key == 0u) m = -INFINITY;
  else {
    unsigned b = (key & 0x80000000u) ? (key & 0x7FFFFFFFu) : ~key;
    m = __uint_as_float(b);
  }
  float ev = expf(ebuf[i] - m);
  ebuf[i] = ev;
  atomicAdd(&denom[d * H + h], ev);
}

__global__ void edge_coef(const int* __restrict__ dst, float* __restrict__ ebuf,
                          const float* __restrict__ denom, int E, int H) {
  int i = blockIdx.x * blockDim.x + threadIdx.x;
  if (i >= E * H) return;
  int e = i / H, h = i - e * H;
  int d = dst[e];
  ebuf[i] = ebuf[i] / (denom[d * H + h] + 1e-16f);
}

// ---------------- aggregate ----------------
template<int H, int F, bool MEAN, bool ELU>
__global__ __launch_bounds__(256) void aggregate_kernel(const int* __restrict__ row_ptr,
                                                        const int* __restrict__ eperm,
                                                        const int* __restrict__ src,
                                                        const float* __restrict__ coef,
                                                        const float* __restrict__ Wh,
                                                        float* __restrict__ out, int N) {
  constexpr int HF = H * F;
  constexpr int T = 256;
  constexpr int PER = (HF + T - 1) / T;
  int n = blockIdx.x;
  int t = threadIdx.x;
  float acc[PER];
  int hL[PER];
#pragma unroll
  for (int p = 0; p < PER; ++p) {
    acc[p] = 0.f;
    int idx = t + p * T;
    hL[p] = (idx < HF) ? (idx / F) : 0;
  }
  int beg = row_ptr[n], end = row_ptr[n + 1];
  for (int k = beg; k < end; ++k) {
    int e = eperm[k];
    int s = src[e];
    const float* w = Wh + (size_t)s * HF;
    const float* c = coef + (size_t)e * H;
#pragma unroll
    for (int p = 0; p < PER; ++p) {
      int idx = t + p * T;
      if (HF % T == 0 || idx < HF) acc[p] += c[hL[p]] * w[idx];
    }
  }
  if constexpr (!MEAN) {
#pragma unroll
    for (int p = 0; p < PER; ++p) {
      int idx = t + p * T;
      if (HF % T == 0 || idx < HF) {
        float v = acc[p];
        if (ELU) v = v > 0.f ? v : expm1f(v);
        out[(size_t)n * HF + idx] = v;
      }
    }
  } else {
    __shared__ float buf[HF];
#pragma unroll
    for (int p = 0; p < PER; ++p) {
      int idx = t + p * T;
      if (idx < HF) buf[idx] = acc[p];
    }
    __syncthreads();
    for (int f = t; f < F; f += T) {
      float s = 0.f;
#pragma unroll
      for (int h = 0; h < H; ++h) s += buf[h * F + f];
      out[(size_t)n * F + f] = s * (1.0f / H);
    }
  }
}

extern "C" void kernel_launch(void* const* d_in, const int* in_sizes, int n_in,
                              void* d_out, int out_size, void* d_ws, size_t ws_size,
                              hipStream_t stream) {
  const float* x  = (const float*)d_in[0];
  const int* eidx = (const int*)d_in[1];
  const float* W1 = (const float*)d_in[2];
  const float* a1 = (const float*)d_in[3];
  const float* W2 = (const float*)d_in[4];
  const float* a2 = (const float*)d_in[5];
  const float* W3 = (const float*)d_in[6];
  const float* a3 = (const float*)d_in[7];
  float* out = (float*)d_out;

  const int N = NN, E = NE;
  const int* src = eidx;
  const int* dst = eidx + E;

  char* ws = (char*)d_ws;
  size_t off = 0;
  auto alloc = [&](size_t bytes) -> void* {
    void* p = ws + off;
    off += (bytes + 255) & ~(size_t)255;
    return p;
  };
  float* Wh = (float*)alloc((size_t)N * 1024 * 4);
  float* h1 = (float*)alloc((size_t)N * 1024 * 4);
  float* h2 = (float*)alloc((size_t)N * 1024 * 4);
  // overlay: weight-split buffers (GEMM phase) vs ebuf (edge phase) — disjoint lifetimes
  char* ov = (char*)alloc(2 * (size_t)1024 * 1024 * 2);   // 4 MiB (>= ebuf 3.84 MB)
  short* whi = (short*)ov;
  short* wlo = whi + (size_t)1024 * 1024;
  float* ebuf = (float*)ov;
  float* atts    = (float*)alloc((size_t)N * 6 * 4);
  float* attd    = (float*)alloc((size_t)N * 6 * 4);
  unsigned* mkey = (unsigned*)alloc((size_t)N * 6 * 4);
  float* denom   = (float*)alloc((size_t)N * 6 * 4);
  int* counts    = (int*)alloc((size_t)N * 4);
  int* row_ptr   = (int*)alloc((size_t)(N + 1) * 4);
  int* cursor    = (int*)alloc((size_t)N * 4);
  int* eperm     = (int*)alloc((size_t)E * 4);

  // ---- CSR by dst ----
  hipMemsetAsync(counts, 0, (size_t)N * 4, stream);
  count_kernel<<<(E + 255) / 256, 256, 0, stream>>>(dst, counts, E);
  scan_kernel<<<1, 1024, 0, stream>>>(counts, row_ptr, cursor, N);
  scatter_kernel<<<(E + 255) / 256, 256, 0, stream>>>(dst, cursor, eperm, E);

  auto run_edges = [&](int H, const float* as_, const float* ad_) {
    int total = E * H;
    hipMemsetAsync(mkey, 0, (size_t)N * H * 4, stream);
    hipMemsetAsync(denom, 0, (size_t)N * H * 4, stream);
    edge_logit_max<<<(total + 255) / 256, 256, 0, stream>>>(src, dst, as_, ad_, ebuf, mkey, E, H);
    edge_exp_sum<<<(total + 255) / 256, 256, 0, stream>>>(dst, mkey, ebuf, denom, E, H);
    edge_coef<<<(total + 255) / 256, 256, 0, stream>>>(dst, ebuf, denom, E, H);
  };

  const int mblocks = (N + 127) / 128;   // 79

  // ---- layer 1: x[10000,50] @ W1[50,1024] ----
  split_w_kernel<<<(1024 * 64 + 255) / 256, 256, 0, stream>>>(W1, whi, wlo, 50, 1024, 1024, 64);
  gemm_mfma<false, false><<<dim3(8, mblocks), 256, 0, stream>>>(x, nullptr, whi, wlo, Wh, N, 1024, 50, 64);
  att_kernel<4, 256><<<N, 256, 0, stream>>>(Wh, a1, atts, attd, N);
  run_edges(4, atts, attd);
  aggregate_kernel<4, 256, false, true><<<N, 256, 0, stream>>>(row_ptr, eperm, src, ebuf, Wh, h1, N);

  // ---- layer 2: h1 @ W2[1024,1024] ----
  split_w_kernel<<<(1024 * 1024 + 255) / 256, 256, 0, stream>>>(W2, whi, wlo, 1024, 1024, 1024, 1024);
  gemm_mfma<false, true><<<dim3(8, mblocks), 256, 0, stream>>>(h1, nullptr, whi, wlo, Wh, N, 1024, 1024, 1024);
  att_kernel<4, 256><<<N, 256, 0, stream>>>(Wh, a2, atts, attd, N);
  run_edges(4, atts, attd);
  aggregate_kernel<4, 256, false, true><<<N, 256, 0, stream>>>(row_ptr, eperm, src, ebuf, Wh, h2, N);

  // ---- layer 3: (h1+h2) @ W3[1024,726], mean over 6 heads ----
  split_w_kernel<<<(768 * 1024 + 255) / 256, 256, 0, stream>>>(W3, whi, wlo, 1024, 726, 768, 1024);
  gemm_mfma<true, true><<<dim3(6, mblocks), 256, 0, stream>>>(h1, h2, whi, wlo, Wh, N, 726, 1024, 1024);
  att_kernel<6, 121><<<N, 384, 0, stream>>>(Wh, a3, atts, attd, N);
  run_edges(6, atts, attd);
  aggregate_kernel<6, 121, true, false><<<N, 256, 0, stream>>>(row_ptr, eperm, src, ebuf, Wh, out, N);
}

// Round 3
// 434.330 us; speedup vs baseline: 3.8247x; 1.5220x over previous
//
#include <hip/hip_runtime.h>
#include <hip/hip_bf16.h>
#include <math.h>

#define NN 10000
#define NE 160000

typedef __attribute__((ext_vector_type(8))) short bf16x8;
typedef __attribute__((ext_vector_type(4))) short bf16x4;
typedef __attribute__((ext_vector_type(4))) float f32x4;

static __device__ __forceinline__ unsigned short f2bf(float f) {
  unsigned u = __builtin_bit_cast(unsigned, f);
  unsigned r = u + 0x7fffu + ((u >> 16) & 1u);   // RNE
  return (unsigned short)(r >> 16);
}
static __device__ __forceinline__ float bf2f(unsigned short s) {
  return __builtin_bit_cast(float, (unsigned)s << 16);
}

// ---------------- CSR build (dst-sorted edge permutation) ----------------
__global__ void count_kernel(const int* __restrict__ dst, int* __restrict__ counts, int E) {
  int e = blockIdx.x * blockDim.x + threadIdx.x;
  if (e < E) atomicAdd(&counts[dst[e]], 1);
}

__global__ __launch_bounds__(1024) void scan_kernel(const int* __restrict__ counts,
                                                    int* __restrict__ row_ptr,
                                                    int* __restrict__ cursor, int N) {
  __shared__ int sums[1024];
  int t = threadIdx.x;
  const int CH = (N + 1023) >> 10;
  int base = t * CH;
  int s = 0;
  for (int i = 0; i < CH; ++i) { int idx = base + i; if (idx < N) s += counts[idx]; }
  sums[t] = s;
  __syncthreads();
  for (int off = 1; off < 1024; off <<= 1) {
    int v = 0;
    if (t >= off) v = sums[t - off];
    __syncthreads();
    if (t >= off) sums[t] += v;
    __syncthreads();
  }
  int run = (t == 0) ? 0 : sums[t - 1];
  for (int i = 0; i < CH; ++i) {
    int idx = base + i;
    if (idx < N) { row_ptr[idx] = run; cursor[idx] = run; run += counts[idx]; }
  }
  if (t == 0) row_ptr[N] = sums[1023];
}

__global__ void scatter_kernel(const int* __restrict__ src, const int* __restrict__ dst,
                               int* __restrict__ cursor, int* __restrict__ ssrc, int E) {
  int e = blockIdx.x * blockDim.x + threadIdx.x;
  if (e < E) {
    int pos = atomicAdd(&cursor[dst[e]], 1);
    ssrc[pos] = src[e];
  }
}

// ---------------- weight split+transpose: W[K][N] fp32 -> Wt_hi/lo [Npad][KP] bf16 ----------------
__global__ void split_w_kernel(const float* __restrict__ W, short* __restrict__ hi,
                               short* __restrict__ lo, int K, int N, int Npad, int KP) {
  int idx = blockIdx.x * blockDim.x + threadIdx.x;
  if (idx >= Npad * KP) return;
  int n = idx / KP, k = idx - n * KP;
  float v = (n < N && k < K) ? W[(size_t)k * N + n] : 0.f;
  unsigned short h = f2bf(v);
  hi[idx] = (short)h;
  lo[idx] = (short)f2bf(v - bf2f(h));
}

// ---------------- split-bf16 MFMA GEMM -> bf16 C ----------------
// 128x128 tile, BK=32, 4 waves (2x2), wave 64x64 via 4x4 16x16x32 MFMA tiles, 3 products.
template<bool ADD2, bool VEC>
__global__ __launch_bounds__(256) void gemm_mfma(const float* __restrict__ A,
                                                 const float* __restrict__ A2,
                                                 const short* __restrict__ Bhi,
                                                 const short* __restrict__ Blo,
                                                 short* __restrict__ C,
                                                 int M, int K, int KP, int NcStore) {
  __shared__ short As_hi[128 * 40];
  __shared__ short As_lo[128 * 40];
  __shared__ short Bs_hi[128 * 40];
  __shared__ short Bs_lo[128 * 40];

  const int t = threadIdx.x;
  const int lane = t & 63;
  const int wid = t >> 6;
  const int wr = wid >> 1;
  const int wc = wid & 1;
  const int row_in = lane & 15;
  const int kgrp = lane >> 4;

  const int m0 = blockIdx.y * 128;
  const int n0 = blockIdx.x * 128;

  f32x4 acc[4][4];
#pragma unroll
  for (int i = 0; i < 4; ++i)
#pragma unroll
    for (int j = 0; j < 4; ++j) acc[i][j] = (f32x4){0.f, 0.f, 0.f, 0.f};

  for (int k0 = 0; k0 < KP; k0 += 32) {
    if (k0) __syncthreads();
#pragma unroll
    for (int i = 0; i < 4; ++i) {
      int lin = (i * 256 + t) * 4;
      int row = lin >> 5;
      int k = lin & 31;
      int gm = m0 + row;
      if (gm >= M) gm = M - 1;
      float v[4];
      if (VEC) {
        f32x4 va = *(const f32x4*)&A[(size_t)gm * K + k0 + k];
        if (ADD2) {
          f32x4 vb = *(const f32x4*)&A2[(size_t)gm * K + k0 + k];
          va += vb;
        }
        v[0] = va.x; v[1] = va.y; v[2] = va.z; v[3] = va.w;
      } else {
#pragma unroll
        for (int e = 0; e < 4; ++e) {
          int gk = k0 + k + e;
          float x = (gk < K) ? A[(size_t)gm * K + gk] : 0.f;
          if (ADD2 && gk < K) x += A2[(size_t)gm * K + gk];
          v[e] = x;
        }
      }
      short h4[4], l4[4];
#pragma unroll
      for (int e = 0; e < 4; ++e) {
        unsigned short h = f2bf(v[e]);
        h4[e] = (short)h;
        l4[e] = (short)f2bf(v[e] - bf2f(h));
      }
      *(bf16x4*)&As_hi[row * 40 + k] = (bf16x4){h4[0], h4[1], h4[2], h4[3]};
      *(bf16x4*)&As_lo[row * 40 + k] = (bf16x4){l4[0], l4[1], l4[2], l4[3]};
    }
#pragma unroll
    for (int r = 0; r < 2; ++r) {
      int lin = (r * 256 + t) * 8;
      int col = lin >> 5;
      int k = lin & 31;
      size_t g = (size_t)(n0 + col) * KP + k0 + k;
      *(bf16x8*)&Bs_hi[col * 40 + k] = *(const bf16x8*)&Bhi[g];
      *(bf16x8*)&Bs_lo[col * 40 + k] = *(const bf16x8*)&Blo[g];
    }
    __syncthreads();

    bf16x8 ah[4], al[4], bh[4], bl[4];
#pragma unroll
    for (int mi = 0; mi < 4; ++mi) {
      int r = (wr * 64 + mi * 16 + row_in) * 40 + kgrp * 8;
      ah[mi] = *(const bf16x8*)&As_hi[r];
      al[mi] = *(const bf16x8*)&As_lo[r];
    }
#pragma unroll
    for (int ni = 0; ni < 4; ++ni) {
      int r = (wc * 64 + ni * 16 + row_in) * 40 + kgrp * 8;
      bh[ni] = *(const bf16x8*)&Bs_hi[r];
      bl[ni] = *(const bf16x8*)&Bs_lo[r];
    }
#pragma unroll
    for (int mi = 0; mi < 4; ++mi)
#pragma unroll
      for (int ni = 0; ni < 4; ++ni) {
        acc[mi][ni] = __builtin_amdgcn_mfma_f32_16x16x32_bf16(ah[mi], bh[ni], acc[mi][ni], 0, 0, 0);
        acc[mi][ni] = __builtin_amdgcn_mfma_f32_16x16x32_bf16(al[mi], bh[ni], acc[mi][ni], 0, 0, 0);
        acc[mi][ni] = __builtin_amdgcn_mfma_f32_16x16x32_bf16(ah[mi], bl[ni], acc[mi][ni], 0, 0, 0);
      }
  }

  // D layout: col = lane&15 (n), row = (lane>>4)*4 + j (m)
#pragma unroll
  for (int mi = 0; mi < 4; ++mi) {
#pragma unroll
    for (int ni = 0; ni < 4; ++ni) {
      int gn = n0 + wc * 64 + ni * 16 + row_in;
      if (gn >= NcStore) continue;
#pragma unroll
      for (int j = 0; j < 4; ++j) {
        int gm = m0 + wr * 64 + mi * 16 + kgrp * 4 + j;
        if (gm < M) C[(size_t)gm * NcStore + gn] = (short)f2bf(acc[mi][ni][j]);
      }
    }
  }
}

// ---------------- attention scores from bf16 Wh ----------------
template<int H, int F, int SW>
__global__ void att_kernel(const short* __restrict__ Whb, const float* __restrict__ a,
                           float* __restrict__ att_s, float* __restrict__ att_d, int N) {
  int n = blockIdx.x;
  int h = threadIdx.x >> 6;
  int lane = threadIdx.x & 63;
  const short* w = Whb + (size_t)n * SW + h * F;
  const float* as = a + (size_t)h * 2 * F;
  const float* ad = as + F;
  float ss = 0.f, sd = 0.f;
  for (int f = lane; f < F; f += 64) {
    float v = bf2f((unsigned short)w[f]);
    ss += v * as[f];
    sd += v * ad[f];
  }
#pragma unroll
  for (int off = 32; off > 0; off >>= 1) {
    ss += __shfl_down(ss, off);
    sd += __shfl_down(sd, off);
  }
  if (lane == 0) {
    att_s[n * H + h] = ss;
    att_d[n * H + h] = sd;
  }
}

// ---------------- fused CSR edge softmax: per dst node, one wave ----------------
// writes UNNORMALIZED ev (CSR order, [k][h]) + denom[n][h]; aggregate divides.
template<int H>
__global__ __launch_bounds__(64) void edge_softmax_csr(const int* __restrict__ row_ptr,
                                                       const int* __restrict__ ssrc,
                                                       const float* __restrict__ att_s,
                                                       const float* __restrict__ att_d,
                                                       float* __restrict__ cbuf,
                                                       float* __restrict__ denom, int N) {
  int n = blockIdx.x;
  int lane = threadIdx.x;
  int beg = row_ptr[n], end = row_ptr[n + 1];
  float ad[H];
#pragma unroll
  for (int h = 0; h < H; ++h) ad[h] = att_d[n * H + h];

  float m[H];
#pragma unroll
  for (int h = 0; h < H; ++h) m[h] = -INFINITY;
  for (int k = beg + lane; k < end; k += 64) {
    int s = ssrc[k];
#pragma unroll
    for (int h = 0; h < H; ++h) {
      float x = att_s[s * H + h] + ad[h];
      float l = x >= 0.f ? x : 0.2f * x;
      m[h] = fmaxf(m[h], l);
    }
  }
#pragma unroll
  for (int h = 0; h < H; ++h)
#pragma unroll
    for (int off = 32; off > 0; off >>= 1) m[h] = fmaxf(m[h], __shfl_xor(m[h], off));

  float sum[H];
#pragma unroll
  for (int h = 0; h < H; ++h) sum[h] = 0.f;
  for (int k = beg + lane; k < end; k += 64) {
    int s = ssrc[k];
#pragma unroll
    for (int h = 0; h < H; ++h) {
      float x = att_s[s * H + h] + ad[h];
      float l = x >= 0.f ? x : 0.2f * x;
      float ev = __expf(l - m[h]);
      cbuf[(size_t)k * H + h] = ev;
      sum[h] += ev;
    }
  }
#pragma unroll
  for (int h = 0; h < H; ++h) {
#pragma unroll
    for (int off = 32; off > 0; off >>= 1) sum[h] += __shfl_xor(sum[h], off);
  }
  if (lane < H) denom[n * H + lane] = sum[lane];
}

// ---------------- aggregate from bf16 Wh, CSR coef ----------------
template<int H, int F, int SW, bool MEAN, bool ELU>
__global__ __launch_bounds__(256) void aggregate_bf16(const int* __restrict__ row_ptr,
                                                      const int* __restrict__ ssrc,
                                                      const float* __restrict__ cbuf,
                                                      const float* __restrict__ denom,
                                                      const short* __restrict__ Whb,
                                                      float* __restrict__ out, int N) {
  constexpr int HF = H * F;
  int n = blockIdx.x;
  int t = threadIdx.x;
  int idx = t * 4;
  bool active = idx < HF;
  int hj[4];
#pragma unroll
  for (int j = 0; j < 4; ++j) {
    int h = (idx + j) / F;
    hj[j] = h < H ? h : H - 1;
  }
  float inv[H];
#pragma unroll
  for (int h = 0; h < H; ++h) inv[h] = 1.f / (denom[n * H + h] + 1e-16f);

  f32x4 acc = (f32x4){0.f, 0.f, 0.f, 0.f};
  int beg = row_ptr[n], end = row_ptr[n + 1];
  if (active) {
    for (int k = beg; k < end; ++k) {
      int s = ssrc[k];
      const float* c = cbuf + (size_t)k * H;
      bf16x4 w = *(const bf16x4*)&Whb[(size_t)s * SW + idx];
#pragma unroll
      for (int j = 0; j < 4; ++j)
        acc[j] += c[hj[j]] * inv[hj[j]] * bf2f((unsigned short)w[j]);
    }
  }
  if constexpr (!MEAN) {
    if (active) {
      f32x4 v = acc;
      if (ELU) {
#pragma unroll
        for (int j = 0; j < 4; ++j) v[j] = v[j] > 0.f ? v[j] : expm1f(v[j]);
      }
      *(f32x4*)&out[(size_t)n * HF + idx] = v;
    }
  } else {
    __shared__ float buf[SW];
    if (active) {
#pragma unroll
      for (int j = 0; j < 4; ++j) buf[idx + j] = (idx + j < HF) ? acc[j] : 0.f;
    }
    __syncthreads();
    for (int f = t; f < F; f += 256) {
      float s = 0.f;
#pragma unroll
      for (int h = 0; h < H; ++h) s += buf[h * F + f];
      out[(size_t)n * F + f] = s * (1.0f / H);
    }
  }
}

extern "C" void kernel_launch(void* const* d_in, const int* in_sizes, int n_in,
                              void* d_out, int out_size, void* d_ws, size_t ws_size,
                              hipStream_t stream) {
  const float* x  = (const float*)d_in[0];
  const int* eidx = (const int*)d_in[1];
  const float* W1 = (const float*)d_in[2];
  const float* a1 = (const float*)d_in[3];
  const float* W2 = (const float*)d_in[4];
  const float* a2 = (const float*)d_in[5];
  const float* W3 = (const float*)d_in[6];
  const float* a3 = (const float*)d_in[7];
  float* out = (float*)d_out;

  const int N = NN, E = NE;
  const int* src = eidx;
  const int* dst = eidx + E;

  char* ws = (char*)d_ws;
  size_t off = 0;
  auto alloc = [&](size_t bytes) -> void* {
    void* p = ws + off;
    off += (bytes + 255) & ~(size_t)255;
    return p;
  };
  short* Whb = (short*)alloc((size_t)N * 1024 * 2);   // bf16 Wh (stride 1024 or 728)
  float* h1  = (float*)alloc((size_t)N * 1024 * 4);
  float* h2  = (float*)alloc((size_t)N * 1024 * 4);
  // overlay: weight split buffers (GEMM phase) vs CSR coef buffer (edge phase)
  char* ov = (char*)alloc((size_t)4 * 1024 * 1024);
  short* whi = (short*)ov;
  short* wlo = whi + (size_t)1024 * 1024;
  float* cbuf = (float*)ov;                            // E*6*4 = 3.84 MB
  float* atts  = (float*)alloc((size_t)N * 6 * 4);
  float* attd  = (float*)alloc((size_t)N * 6 * 4);
  float* denom = (float*)alloc((size_t)N * 6 * 4);
  int* counts  = (int*)alloc((size_t)N * 4);
  int* row_ptr = (int*)alloc((size_t)(N + 1) * 4);
  int* cursor  = (int*)alloc((size_t)N * 4);
  int* ssrc    = (int*)alloc((size_t)E * 4);

  // ---- CSR by dst ----
  hipMemsetAsync(counts, 0, (size_t)N * 4, stream);
  count_kernel<<<(E + 255) / 256, 256, 0, stream>>>(dst, counts, E);
  scan_kernel<<<1, 1024, 0, stream>>>(counts, row_ptr, cursor, N);
  scatter_kernel<<<(E + 255) / 256, 256, 0, stream>>>(src, dst, cursor, ssrc, E);

  const int mblocks = (N + 127) / 128;   // 79

  // ---- layer 1: x[10000,50] @ W1[50,1024] ----
  split_w_kernel<<<(1024 * 64 + 255) / 256, 256, 0, stream>>>(W1, whi, wlo, 50, 1024, 1024, 64);
  gemm_mfma<false, false><<<dim3(8, mblocks), 256, 0, stream>>>(x, nullptr, whi, wlo, Whb, N, 50, 64, 1024);
  att_kernel<4, 256, 1024><<<N, 256, 0, stream>>>(Whb, a1, atts, attd, N);
  edge_softmax_csr<4><<<N, 64, 0, stream>>>(row_ptr, ssrc, atts, attd, cbuf, denom, N);
  aggregate_bf16<4, 256, 1024, false, true><<<N, 256, 0, stream>>>(row_ptr, ssrc, cbuf, denom, Whb, h1, N);

  // ---- layer 2: h1 @ W2[1024,1024] ----
  split_w_kernel<<<(1024 * 1024 + 255) / 256, 256, 0, stream>>>(W2, whi, wlo, 1024, 1024, 1024, 1024);
  gemm_mfma<false, true><<<dim3(8, mblocks), 256, 0, stream>>>(h1, nullptr, whi, wlo, Whb, N, 1024, 1024, 1024);
  att_kernel<4, 256, 1024><<<N, 256, 0, stream>>>(Whb, a2, atts, attd, N);
  edge_softmax_csr<4><<<N, 64, 0, stream>>>(row_ptr, ssrc, atts, attd, cbuf, denom, N);
  aggregate_bf16<4, 256, 1024, false, true><<<N, 256, 0, stream>>>(row_ptr, ssrc, cbuf, denom, Whb, h2, N);

  // ---- layer 3: (h1+h2) @ W3[1024,726] -> bf16 stride 728, mean over 6 heads ----
  split_w_kernel<<<(768 * 1024 + 255) / 256, 256, 0, stream>>>(W3, whi, wlo, 1024, 726, 768, 1024);
  gemm_mfma<true, true><<<dim3(6, mblocks), 256, 0, stream>>>(h1, h2, whi, wlo, Whb, N, 1024, 1024, 728);
  att_kernel<6, 121, 728><<<N, 384, 0, stream>>>(Whb, a3, atts, attd, N);
  edge_softmax_csr<6><<<N, 64, 0, stream>>>(row_ptr, ssrc, atts, attd, cbuf, denom, N);
  aggregate_bf16<6, 121, 728, true, false><<<N, 256, 0, stream>>>(row_ptr, ssrc, cbuf, denom, Whb, out, N);
}

// Round 4
// 411.980 us; speedup vs baseline: 4.0321x; 1.0543x over previous
//
#include <hip/hip_runtime.h>
#include <hip/hip_bf16.h>
#include <math.h>

#define NN 10000
#define NE 160000

typedef __attribute__((ext_vector_type(8))) short bf16x8;
typedef __attribute__((ext_vector_type(4))) short bf16x4;
typedef __attribute__((ext_vector_type(4))) float f32x4;

static __device__ __forceinline__ unsigned short f2bf(float f) {
  unsigned u = __builtin_bit_cast(unsigned, f);
  unsigned r = u + 0x7fffu + ((u >> 16) & 1u);   // RNE
  return (unsigned short)(r >> 16);
}
static __device__ __forceinline__ float bf2f(unsigned short s) {
  return __builtin_bit_cast(float, (unsigned)s << 16);
}

// ---------------- CSR build ----------------
__global__ void count_kernel(const int* __restrict__ dst, int* __restrict__ counts, int E) {
  int e = blockIdx.x * blockDim.x + threadIdx.x;
  if (e < E) atomicAdd(&counts[dst[e]], 1);
}

__global__ __launch_bounds__(1024) void scan_kernel(const int* __restrict__ counts,
                                                    int* __restrict__ row_ptr,
                                                    int* __restrict__ cursor, int N) {
  __shared__ int sums[1024];
  int t = threadIdx.x;
  const int CH = (N + 1023) >> 10;
  int base = t * CH;
  int s = 0;
  for (int i = 0; i < CH; ++i) { int idx = base + i; if (idx < N) s += counts[idx]; }
  sums[t] = s;
  __syncthreads();
  for (int off = 1; off < 1024; off <<= 1) {
    int v = 0;
    if (t >= off) v = sums[t - off];
    __syncthreads();
    if (t >= off) sums[t] += v;
    __syncthreads();
  }
  int run = (t == 0) ? 0 : sums[t - 1];
  for (int i = 0; i < CH; ++i) {
    int idx = base + i;
    if (idx < N) { row_ptr[idx] = run; cursor[idx] = run; run += counts[idx]; }
  }
  if (t == 0) row_ptr[N] = sums[1023];
}

__global__ void scatter_kernel(const int* __restrict__ src, const int* __restrict__ dst,
                               int* __restrict__ cursor, int* __restrict__ ssrc, int E) {
  int e = blockIdx.x * blockDim.x + threadIdx.x;
  if (e < E) {
    int pos = atomicAdd(&cursor[dst[e]], 1);
    ssrc[pos] = src[e];
  }
}

// ---------------- weight split+transpose: W[K][N] -> [Npad][KP] bf16 hi/lo ----------------
__global__ void split_w_kernel(const float* __restrict__ W, short* __restrict__ hi,
                               short* __restrict__ lo, int K, int N, int Npad, int KP) {
  int idx = blockIdx.x * blockDim.x + threadIdx.x;
  if (idx >= Npad * KP) return;
  int n = idx / KP, k = idx - n * KP;
  float v = (n < N && k < K) ? W[(size_t)k * N + n] : 0.f;
  unsigned short h = f2bf(v);
  hi[idx] = (short)h;
  lo[idx] = (short)f2bf(v - bf2f(h));
}

// ---------------- activation split: A[M][K] fp32 -> [M][KP] bf16 hi/lo ----------------
__global__ void split_a_kernel(const float* __restrict__ A, short* __restrict__ hi,
                               short* __restrict__ lo, int M, int K, int KP) {
  int idx = blockIdx.x * blockDim.x + threadIdx.x;
  if (idx >= M * KP) return;
  int m = idx / KP, k = idx - m * KP;
  float v = (k < K) ? A[(size_t)m * K + k] : 0.f;
  unsigned short h = f2bf(v);
  hi[idx] = (short)h;
  lo[idx] = (short)f2bf(v - bf2f(h));
}

// ---------------- split-bf16 MFMA GEMM, pre-split A & B, XCD-swizzled blocks ----------------
// 128x128 tile, BK=32, 4 waves (2x2); C bf16 [M][NcStore].
__global__ __launch_bounds__(256) void gemm_mfma(const short* __restrict__ Ahi,
                                                 const short* __restrict__ Alo,
                                                 const short* __restrict__ Bhi,
                                                 const short* __restrict__ Blo,
                                                 short* __restrict__ C,
                                                 int M, int KP, int NcStore, int NC) {
  // swizzle: all col-blocks of a row-panel on the same XCD, consecutively
  int flat = blockIdx.x;
  int xcd = flat & 7;
  int slot = flat >> 3;
  int cblk = slot % NC;
  int rblk = (slot / NC) * 8 + xcd;
  const int m0 = rblk * 128;
  if (m0 >= M) return;
  const int n0 = cblk * 128;

  __shared__ short As_hi[128 * 40];
  __shared__ short As_lo[128 * 40];
  __shared__ short Bs_hi[128 * 40];
  __shared__ short Bs_lo[128 * 40];

  const int t = threadIdx.x;
  const int lane = t & 63;
  const int wid = t >> 6;
  const int wr = wid >> 1;
  const int wc = wid & 1;
  const int row_in = lane & 15;
  const int kgrp = lane >> 4;

  f32x4 acc[4][4];
#pragma unroll
  for (int i = 0; i < 4; ++i)
#pragma unroll
    for (int j = 0; j < 4; ++j) acc[i][j] = (f32x4){0.f, 0.f, 0.f, 0.f};

  for (int k0 = 0; k0 < KP; k0 += 32) {
    if (k0) __syncthreads();
    // ---- stage A (pre-split, pure copy) ----
#pragma unroll
    for (int i = 0; i < 2; ++i) {
      int lin = (i * 256 + t) * 8;
      int row = lin >> 5;
      int k = lin & 31;
      int gm = m0 + row;
      if (gm >= M) gm = M - 1;
      size_t g = (size_t)gm * KP + k0 + k;
      *(bf16x8*)&As_hi[row * 40 + k] = *(const bf16x8*)&Ahi[g];
      *(bf16x8*)&As_lo[row * 40 + k] = *(const bf16x8*)&Alo[g];
    }
    // ---- stage B ----
#pragma unroll
    for (int r = 0; r < 2; ++r) {
      int lin = (r * 256 + t) * 8;
      int col = lin >> 5;
      int k = lin & 31;
      size_t g = (size_t)(n0 + col) * KP + k0 + k;
      *(bf16x8*)&Bs_hi[col * 40 + k] = *(const bf16x8*)&Bhi[g];
      *(bf16x8*)&Bs_lo[col * 40 + k] = *(const bf16x8*)&Blo[g];
    }
    __syncthreads();

    bf16x8 ah[4], al[4], bh[4], bl[4];
#pragma unroll
    for (int mi = 0; mi < 4; ++mi) {
      int r = (wr * 64 + mi * 16 + row_in) * 40 + kgrp * 8;
      ah[mi] = *(const bf16x8*)&As_hi[r];
      al[mi] = *(const bf16x8*)&As_lo[r];
    }
#pragma unroll
    for (int ni = 0; ni < 4; ++ni) {
      int r = (wc * 64 + ni * 16 + row_in) * 40 + kgrp * 8;
      bh[ni] = *(const bf16x8*)&Bs_hi[r];
      bl[ni] = *(const bf16x8*)&Bs_lo[r];
    }
#pragma unroll
    for (int mi = 0; mi < 4; ++mi)
#pragma unroll
      for (int ni = 0; ni < 4; ++ni) {
        acc[mi][ni] = __builtin_amdgcn_mfma_f32_16x16x32_bf16(ah[mi], bh[ni], acc[mi][ni], 0, 0, 0);
        acc[mi][ni] = __builtin_amdgcn_mfma_f32_16x16x32_bf16(al[mi], bh[ni], acc[mi][ni], 0, 0, 0);
        acc[mi][ni] = __builtin_amdgcn_mfma_f32_16x16x32_bf16(ah[mi], bl[ni], acc[mi][ni], 0, 0, 0);
      }
  }

  // D layout: col = lane&15 (n), row = (lane>>4)*4 + j (m)
#pragma unroll
  for (int mi = 0; mi < 4; ++mi) {
#pragma unroll
    for (int ni = 0; ni < 4; ++ni) {
      int gn = n0 + wc * 64 + ni * 16 + row_in;
      if (gn >= NcStore) continue;
#pragma unroll
      for (int j = 0; j < 4; ++j) {
        int gm = m0 + wr * 64 + mi * 16 + kgrp * 4 + j;
        if (gm < M) C[(size_t)gm * NcStore + gn] = (short)f2bf(acc[mi][ni][j]);
      }
    }
  }
}

// ---------------- attention scores from bf16 Wh ----------------
template<int H, int F, int SW>
__global__ void att_kernel(const short* __restrict__ Whb, const float* __restrict__ a,
                           float* __restrict__ att_s, float* __restrict__ att_d, int N) {
  int n = blockIdx.x;
  int h = threadIdx.x >> 6;
  int lane = threadIdx.x & 63;
  const short* w = Whb + (size_t)n * SW + h * F;
  const float* as = a + (size_t)h * 2 * F;
  const float* ad = as + F;
  float ss = 0.f, sd = 0.f;
  for (int f = lane; f < F; f += 64) {
    float v = bf2f((unsigned short)w[f]);
    ss += v * as[f];
    sd += v * ad[f];
  }
#pragma unroll
  for (int off = 32; off > 0; off >>= 1) {
    ss += __shfl_down(ss, off);
    sd += __shfl_down(sd, off);
  }
  if (lane == 0) {
    att_s[n * H + h] = ss;
    att_d[n * H + h] = sd;
  }
}

// ---------------- fused CSR edge softmax: per dst node, one wave; NORMALIZED coefs ----------------
template<int H>
__global__ __launch_bounds__(64) void edge_softmax_csr(const int* __restrict__ row_ptr,
                                                       const int* __restrict__ ssrc,
                                                       const float* __restrict__ att_s,
                                                       const float* __restrict__ att_d,
                                                       float* __restrict__ cbuf, int N) {
  int n = blockIdx.x;
  int lane = threadIdx.x;
  int beg = row_ptr[n], end = row_ptr[n + 1];
  float ad[H];
#pragma unroll
  for (int h = 0; h < H; ++h) ad[h] = att_d[n * H + h];

  float m[H];
#pragma unroll
  for (int h = 0; h < H; ++h) m[h] = -INFINITY;
  for (int k = beg + lane; k < end; k += 64) {
    int s = ssrc[k];
#pragma unroll
    for (int h = 0; h < H; ++h) {
      float x = att_s[s * H + h] + ad[h];
      float l = x >= 0.f ? x : 0.2f * x;
      m[h] = fmaxf(m[h], l);
    }
  }
#pragma unroll
  for (int h = 0; h < H; ++h)
#pragma unroll
    for (int off = 32; off > 0; off >>= 1) m[h] = fmaxf(m[h], __shfl_xor(m[h], off));

  float sum[H];
#pragma unroll
  for (int h = 0; h < H; ++h) sum[h] = 0.f;
  for (int k = beg + lane; k < end; k += 64) {
    int s = ssrc[k];
#pragma unroll
    for (int h = 0; h < H; ++h) {
      float x = att_s[s * H + h] + ad[h];
      float l = x >= 0.f ? x : 0.2f * x;
      float ev = __expf(l - m[h]);
      cbuf[(size_t)k * H + h] = ev;
      sum[h] += ev;
    }
  }
#pragma unroll
  for (int h = 0; h < H; ++h) {
#pragma unroll
    for (int off = 32; off > 0; off >>= 1) sum[h] += __shfl_xor(sum[h], off);
    sum[h] = 1.f / (sum[h] + 1e-16f);
  }
  for (int k = beg + lane; k < end; k += 64) {
#pragma unroll
    for (int h = 0; h < H; ++h) cbuf[(size_t)k * H + h] *= sum[h];
  }
}

// ---------------- aggregate for concat layers (H=4,F=256): 2 nodes / 256-thr block ----------------
// MODE 0: out = split(elu(agg))          (layer 1 -> h1 hi/lo)
// MODE 1: out = split(h1 + elu(agg))     (layer 2 -> hsum hi/lo; h1 reconstructed from hi/lo)
template<int MODE>
__global__ __launch_bounds__(256) void aggregate_cat(const int* __restrict__ row_ptr,
                                                     const int* __restrict__ ssrc,
                                                     const float* __restrict__ cbuf,
                                                     const short* __restrict__ Whb,
                                                     const short* __restrict__ h1hi,
                                                     const short* __restrict__ h1lo,
                                                     short* __restrict__ outhi,
                                                     short* __restrict__ outlo, int N) {
  int half = threadIdx.x >> 7;
  int tt = threadIdx.x & 127;
  int n = blockIdx.x * 2 + half;
  if (n >= N) return;
  int idx = tt * 8;
  int h = idx >> 8;   // F=256: all 8 elems in same head

  float acc[8] = {};
  int beg = row_ptr[n], end = row_ptr[n + 1];
  int k = beg;
  for (; k + 1 < end; k += 2) {
    int s0 = ssrc[k], s1 = ssrc[k + 1];
    float c0 = cbuf[(size_t)k * 4 + h];
    float c1 = cbuf[(size_t)(k + 1) * 4 + h];
    bf16x8 w0 = *(const bf16x8*)&Whb[(size_t)s0 * 1024 + idx];
    bf16x8 w1 = *(const bf16x8*)&Whb[(size_t)s1 * 1024 + idx];
#pragma unroll
    for (int j = 0; j < 8; ++j) {
      acc[j] += c0 * bf2f((unsigned short)w0[j]);
      acc[j] += c1 * bf2f((unsigned short)w1[j]);
    }
  }
  if (k < end) {
    int s0 = ssrc[k];
    float c0 = cbuf[(size_t)k * 4 + h];
    bf16x8 w0 = *(const bf16x8*)&Whb[(size_t)s0 * 1024 + idx];
#pragma unroll
    for (int j = 0; j < 8; ++j) acc[j] += c0 * bf2f((unsigned short)w0[j]);
  }

  bf16x8 vhi, vlo;
  size_t o = (size_t)n * 1024 + idx;
  bf16x8 r1h, r1l;
  if (MODE == 1) {
    r1h = *(const bf16x8*)&h1hi[o];
    r1l = *(const bf16x8*)&h1lo[o];
  }
#pragma unroll
  for (int j = 0; j < 8; ++j) {
    float v = acc[j];
    v = v > 0.f ? v : expm1f(v);
    if (MODE == 1) v += bf2f((unsigned short)r1h[j]) + bf2f((unsigned short)r1l[j]);
    unsigned short hb = f2bf(v);
    vhi[j] = (short)hb;
    vlo[j] = (short)f2bf(v - bf2f(hb));
  }
  *(bf16x8*)&outhi[o] = vhi;
  *(bf16x8*)&outlo[o] = vlo;
}

// ---------------- aggregate for mean layer (H=6,F=121,SW=728) -> fp32 out ----------------
__global__ __launch_bounds__(256) void aggregate_mean(const int* __restrict__ row_ptr,
                                                      const int* __restrict__ ssrc,
                                                      const float* __restrict__ cbuf,
                                                      const short* __restrict__ Whb,
                                                      float* __restrict__ out, int N) {
  constexpr int H = 6, F = 121, HF = 726, SW = 728;
  int n = blockIdx.x;
  int t = threadIdx.x;
  int idx = t * 4;
  bool active = idx < HF;
  int hj[4];
#pragma unroll
  for (int j = 0; j < 4; ++j) {
    int h = (idx + j) / F;
    hj[j] = h < H ? h : H - 1;
  }
  f32x4 acc = (f32x4){0.f, 0.f, 0.f, 0.f};
  int beg = row_ptr[n], end = row_ptr[n + 1];
  if (active) {
    for (int k = beg; k < end; ++k) {
      int s = ssrc[k];
      const float* c = cbuf + (size_t)k * H;
      bf16x4 w = *(const bf16x4*)&Whb[(size_t)s * SW + idx];
#pragma unroll
      for (int j = 0; j < 4; ++j)
        acc[j] += c[hj[j]] * bf2f((unsigned short)w[j]);
    }
  }
  __shared__ float buf[SW];
  if (active) {
#pragma unroll
    for (int j = 0; j < 4; ++j)
      if (idx + j < HF) buf[idx + j] = acc[j];
  }
  __syncthreads();
  for (int f = t; f < F; f += 256) {
    float s = 0.f;
#pragma unroll
    for (int h = 0; h < H; ++h) s += buf[h * F + f];
    out[(size_t)n * F + f] = s * (1.0f / H);
  }
}

extern "C" void kernel_launch(void* const* d_in, const int* in_sizes, int n_in,
                              void* d_out, int out_size, void* d_ws, size_t ws_size,
                              hipStream_t stream) {
  const float* x  = (const float*)d_in[0];
  const int* eidx = (const int*)d_in[1];
  const float* W1 = (const float*)d_in[2];
  const float* a1 = (const float*)d_in[3];
  const float* W2 = (const float*)d_in[4];
  const float* a2 = (const float*)d_in[5];
  const float* W3 = (const float*)d_in[6];
  const float* a3 = (const float*)d_in[7];
  float* out = (float*)d_out;

  const int N = NN, E = NE;
  const int* src = eidx;
  const int* dst = eidx + E;

  char* ws = (char*)d_ws;
  size_t off = 0;
  auto alloc = [&](size_t bytes) -> void* {
    void* p = ws + off;
    off += (bytes + 255) & ~(size_t)255;
    return p;
  };
  short* Whb  = (short*)alloc((size_t)N * 1024 * 2);   // bf16 Wh (stride 1024 or 728)
  short* h1hi = (short*)alloc((size_t)N * 1024 * 2);
  short* h1lo = (short*)alloc((size_t)N * 1024 * 2);
  short* shi  = (short*)alloc((size_t)N * 1024 * 2);   // h1 + h2, pre-split
  short* slo  = (short*)alloc((size_t)N * 1024 * 2);
  short* xhi  = (short*)alloc((size_t)N * 64 * 2);
  short* xlo  = (short*)alloc((size_t)N * 64 * 2);
  // overlay: weight split buffers (GEMM phase) vs CSR coef buffer (edge phase)
  char* ov = (char*)alloc((size_t)4 * 1024 * 1024);
  short* whi = (short*)ov;
  short* wlo = whi + (size_t)1024 * 1024;
  float* cbuf = (float*)ov;                            // E*6*4 = 3.84 MB
  float* atts  = (float*)alloc((size_t)N * 6 * 4);
  float* attd  = (float*)alloc((size_t)N * 6 * 4);
  int* counts  = (int*)alloc((size_t)N * 4);
  int* row_ptr = (int*)alloc((size_t)(N + 1) * 4);
  int* cursor  = (int*)alloc((size_t)N * 4);
  int* ssrc    = (int*)alloc((size_t)E * 4);

  // ---- CSR by dst ----
  hipMemsetAsync(counts, 0, (size_t)N * 4, stream);
  count_kernel<<<(E + 255) / 256, 256, 0, stream>>>(dst, counts, E);
  scan_kernel<<<1, 1024, 0, stream>>>(counts, row_ptr, cursor, N);
  scatter_kernel<<<(E + 255) / 256, 256, 0, stream>>>(src, dst, cursor, ssrc, E);

  const int RPG = 10;                 // ceil(79 row-blocks / 8 XCDs)

  // ---- layer 1: x[10000,50] @ W1[50,1024] ----
  split_a_kernel<<<(N * 64 + 255) / 256, 256, 0, stream>>>(x, xhi, xlo, N, 50, 64);
  split_w_kernel<<<(1024 * 64 + 255) / 256, 256, 0, stream>>>(W1, whi, wlo, 50, 1024, 1024, 64);
  gemm_mfma<<<8 * RPG * 8, 256, 0, stream>>>(xhi, xlo, whi, wlo, Whb, N, 64, 1024, 8);
  att_kernel<4, 256, 1024><<<N, 256, 0, stream>>>(Whb, a1, atts, attd, N);
  edge_softmax_csr<4><<<N, 64, 0, stream>>>(row_ptr, ssrc, atts, attd, cbuf, N);
  aggregate_cat<0><<<(N + 1) / 2, 256, 0, stream>>>(row_ptr, ssrc, cbuf, Whb, nullptr, nullptr, h1hi, h1lo, N);

  // ---- layer 2: h1 @ W2[1024,1024]; aggregate emits hsum = h1 + elu(agg) ----
  split_w_kernel<<<(1024 * 1024 + 255) / 256, 256, 0, stream>>>(W2, whi, wlo, 1024, 1024, 1024, 1024);
  gemm_mfma<<<8 * RPG * 8, 256, 0, stream>>>(h1hi, h1lo, whi, wlo, Whb, N, 1024, 1024, 8);
  att_kernel<4, 256, 1024><<<N, 256, 0, stream>>>(Whb, a2, atts, attd, N);
  edge_softmax_csr<4><<<N, 64, 0, stream>>>(row_ptr, ssrc, atts, attd, cbuf, N);
  aggregate_cat<1><<<(N + 1) / 2, 256, 0, stream>>>(row_ptr, ssrc, cbuf, Whb, h1hi, h1lo, shi, slo, N);

  // ---- layer 3: hsum @ W3[1024,726] -> bf16 stride 728, mean over 6 heads ----
  split_w_kernel<<<(768 * 1024 + 255) / 256, 256, 0, stream>>>(W3, whi, wlo, 1024, 726, 768, 1024);
  gemm_mfma<<<8 * RPG * 6, 256, 0, stream>>>(shi, slo, whi, wlo, Whb, N, 1024, 728, 6);
  att_kernel<6, 121, 728><<<N, 384, 0, stream>>>(Whb, a3, atts, attd, N);
  edge_softmax_csr<6><<<N, 64, 0, stream>>>(row_ptr, ssrc, atts, attd, cbuf, N);
  aggregate_mean<<<N, 256, 0, stream>>>(row_ptr, ssrc, cbuf, Whb, out, N);
}

// Round 5
// 322.846 us; speedup vs baseline: 5.1454x; 1.2761x over previous
//
#include <hip/hip_runtime.h>
#include <hip/hip_bf16.h>
#include <math.h>

#define NN 10000
#define NE 160000

typedef __attribute__((ext_vector_type(8))) _Float16 f16x8;
typedef __attribute__((ext_vector_type(4))) _Float16 f16x4;
typedef __attribute__((ext_vector_type(4))) float f32x4;

// ---------------- CSR build ----------------
__global__ void count_kernel(const int* __restrict__ dst, int* __restrict__ counts, int E) {
  int e = blockIdx.x * blockDim.x + threadIdx.x;
  if (e < E) atomicAdd(&counts[dst[e]], 1);
}

__global__ __launch_bounds__(1024) void scan_kernel(const int* __restrict__ counts,
                                                    int* __restrict__ row_ptr,
                                                    int* __restrict__ cursor, int N) {
  __shared__ int sums[1024];
  int t = threadIdx.x;
  const int CH = (N + 1023) >> 10;
  int base = t * CH;
  int s = 0;
  for (int i = 0; i < CH; ++i) { int idx = base + i; if (idx < N) s += counts[idx]; }
  sums[t] = s;
  __syncthreads();
  for (int off = 1; off < 1024; off <<= 1) {
    int v = 0;
    if (t >= off) v = sums[t - off];
    __syncthreads();
    if (t >= off) sums[t] += v;
    __syncthreads();
  }
  int run = (t == 0) ? 0 : sums[t - 1];
  for (int i = 0; i < CH; ++i) {
    int idx = base + i;
    if (idx < N) { row_ptr[idx] = run; cursor[idx] = run; run += counts[idx]; }
  }
  if (t == 0) row_ptr[N] = sums[1023];
}

__global__ void scatter_kernel(const int* __restrict__ src, const int* __restrict__ dst,
                               int* __restrict__ cursor, int* __restrict__ ssrc, int E) {
  int e = blockIdx.x * blockDim.x + threadIdx.x;
  if (e < E) {
    int pos = atomicAdd(&cursor[dst[e]], 1);
    ssrc[pos] = src[e];
  }
}

// ---------------- prep: all weight transposes + x conversion to fp16, one kernel ----------------
#define SEG0 (NN * 64)        // x [10000][50] -> xh [10000][64]
#define SEG1 (1024 * 64)      // W1 [50][1024] -> w1 [1024][64]
#define SEG2 (1024 * 1024)    // W2 [1024][1024] -> w2 [1024][1024]
#define SEG3 (768 * 1024)     // W3 [1024][726] -> w3 [768][1024]
__global__ void prep_kernel(const float* __restrict__ x, const float* __restrict__ W1,
                            const float* __restrict__ W2, const float* __restrict__ W3,
                            _Float16* __restrict__ xh, _Float16* __restrict__ w1,
                            _Float16* __restrict__ w2, _Float16* __restrict__ w3) {
  int i = blockIdx.x * blockDim.x + threadIdx.x;
  if (i < SEG0) {
    int m = i >> 6, k = i & 63;
    xh[i] = (_Float16)(k < 50 ? x[m * 50 + k] : 0.f);
  } else if (i < SEG0 + SEG1) {
    int j = i - SEG0;
    int n = j >> 6, k = j & 63;
    w1[j] = (_Float16)(k < 50 ? W1[k * 1024 + n] : 0.f);
  } else if (i < SEG0 + SEG1 + SEG2) {
    int j = i - SEG0 - SEG1;
    int n = j >> 10, k = j & 1023;
    w2[j] = (_Float16)W2[k * 1024 + n];
  } else if (i < SEG0 + SEG1 + SEG2 + SEG3) {
    int j = i - SEG0 - SEG1 - SEG2;
    int n = j >> 10, k = j & 1023;
    w3[j] = (_Float16)(n < 726 ? W3[k * 726 + n] : 0.f);
  }
}

// ---------------- fp16 MFMA GEMM, XCD-swizzled, 128x128 tile, BK=64 ----------------
// A [M][KP] f16 row-major, B [Npad][KP] f16 (pre-transposed), C [M][NcStore] f16.
__global__ __launch_bounds__(256) void gemm_f16(const _Float16* __restrict__ A,
                                                const _Float16* __restrict__ B,
                                                _Float16* __restrict__ C,
                                                int M, int KP, int NcStore, int NC) {
  int flat = blockIdx.x;
  int xcd = flat & 7;
  int slot = flat >> 3;
  int cblk = slot % NC;
  int rblk = (slot / NC) * 8 + xcd;
  const int m0 = rblk * 128;
  if (m0 >= M) return;
  const int n0 = cblk * 128;

  __shared__ _Float16 As[128 * 72];
  __shared__ _Float16 Bs[128 * 72];

  const int t = threadIdx.x;
  const int lane = t & 63;
  const int wid = t >> 6;
  const int wr = wid >> 1;
  const int wc = wid & 1;
  const int row_in = lane & 15;
  const int kgrp = lane >> 4;

  f32x4 acc[4][4];
#pragma unroll
  for (int i = 0; i < 4; ++i)
#pragma unroll
    for (int j = 0; j < 4; ++j) acc[i][j] = (f32x4){0.f, 0.f, 0.f, 0.f};

  for (int k0 = 0; k0 < KP; k0 += 64) {
    if (k0) __syncthreads();
#pragma unroll
    for (int i = 0; i < 4; ++i) {
      int lin = (i * 256 + t) * 8;
      int row = lin >> 6;          // 0..127
      int k = lin & 63;
      int gm = m0 + row;
      if (gm >= M) gm = M - 1;
      *(f16x8*)&As[row * 72 + k] = *(const f16x8*)&A[(size_t)gm * KP + k0 + k];
      *(f16x8*)&Bs[row * 72 + k] = *(const f16x8*)&B[(size_t)(n0 + row) * KP + k0 + k];
    }
    __syncthreads();

#pragma unroll
    for (int ks = 0; ks < 64; ks += 32) {
      f16x8 a[4], b[4];
#pragma unroll
      for (int mi = 0; mi < 4; ++mi)
        a[mi] = *(const f16x8*)&As[(wr * 64 + mi * 16 + row_in) * 72 + ks + kgrp * 8];
#pragma unroll
      for (int ni = 0; ni < 4; ++ni)
        b[ni] = *(const f16x8*)&Bs[(wc * 64 + ni * 16 + row_in) * 72 + ks + kgrp * 8];
#pragma unroll
      for (int mi = 0; mi < 4; ++mi)
#pragma unroll
        for (int ni = 0; ni < 4; ++ni)
          acc[mi][ni] = __builtin_amdgcn_mfma_f32_16x16x32_f16(a[mi], b[ni], acc[mi][ni], 0, 0, 0);
    }
  }

  // D layout: col = lane&15 (n), row = (lane>>4)*4 + j (m)
#pragma unroll
  for (int mi = 0; mi < 4; ++mi) {
#pragma unroll
    for (int ni = 0; ni < 4; ++ni) {
      int gn = n0 + wc * 64 + ni * 16 + row_in;
      if (gn >= NcStore) continue;
#pragma unroll
      for (int j = 0; j < 4; ++j) {
        int gm = m0 + wr * 64 + mi * 16 + kgrp * 4 + j;
        if (gm < M) C[(size_t)gm * NcStore + gn] = (_Float16)acc[mi][ni][j];
      }
    }
  }
}

// ---------------- attention scores from fp16 Wh ----------------
template<int H, int F, int SW>
__global__ void att_kernel(const _Float16* __restrict__ Whb, const float* __restrict__ a,
                           float* __restrict__ att_s, float* __restrict__ att_d, int N) {
  int n = blockIdx.x;
  int h = threadIdx.x >> 6;
  int lane = threadIdx.x & 63;
  const _Float16* w = Whb + (size_t)n * SW + h * F;
  const float* as = a + (size_t)h * 2 * F;
  const float* ad = as + F;
  float ss = 0.f, sd = 0.f;
  for (int f = lane; f < F; f += 64) {
    float v = (float)w[f];
    ss += v * as[f];
    sd += v * ad[f];
  }
#pragma unroll
  for (int off = 32; off > 0; off >>= 1) {
    ss += __shfl_down(ss, off);
    sd += __shfl_down(sd, off);
  }
  if (lane == 0) {
    att_s[n * H + h] = ss;
    att_d[n * H + h] = sd;
  }
}

// ---------------- fused CSR edge softmax (normalized coefs) ----------------
template<int H>
__global__ __launch_bounds__(64) void edge_softmax_csr(const int* __restrict__ row_ptr,
                                                       const int* __restrict__ ssrc,
                                                       const float* __restrict__ att_s,
                                                       const float* __restrict__ att_d,
                                                       float* __restrict__ cbuf, int N) {
  int n = blockIdx.x;
  int lane = threadIdx.x;
  int beg = row_ptr[n], end = row_ptr[n + 1];
  float ad[H];
#pragma unroll
  for (int h = 0; h < H; ++h) ad[h] = att_d[n * H + h];

  float m[H];
#pragma unroll
  for (int h = 0; h < H; ++h) m[h] = -INFINITY;
  for (int k = beg + lane; k < end; k += 64) {
    int s = ssrc[k];
#pragma unroll
    for (int h = 0; h < H; ++h) {
      float x = att_s[s * H + h] + ad[h];
      float l = x >= 0.f ? x : 0.2f * x;
      m[h] = fmaxf(m[h], l);
    }
  }
#pragma unroll
  for (int h = 0; h < H; ++h)
#pragma unroll
    for (int off = 32; off > 0; off >>= 1) m[h] = fmaxf(m[h], __shfl_xor(m[h], off));

  float sum[H];
#pragma unroll
  for (int h = 0; h < H; ++h) sum[h] = 0.f;
  for (int k = beg + lane; k < end; k += 64) {
    int s = ssrc[k];
#pragma unroll
    for (int h = 0; h < H; ++h) {
      float x = att_s[s * H + h] + ad[h];
      float l = x >= 0.f ? x : 0.2f * x;
      float ev = __expf(l - m[h]);
      cbuf[(size_t)k * H + h] = ev;
      sum[h] += ev;
    }
  }
#pragma unroll
  for (int h = 0; h < H; ++h) {
#pragma unroll
    for (int off = 32; off > 0; off >>= 1) sum[h] += __shfl_xor(sum[h], off);
    sum[h] = 1.f / (sum[h] + 1e-16f);
  }
  for (int k = beg + lane; k < end; k += 64) {
#pragma unroll
    for (int h = 0; h < H; ++h) cbuf[(size_t)k * H + h] *= sum[h];
  }
}

// ---------------- aggregate for concat layers (H=4,F=256): 2 nodes / 256-thr block ----------------
// MODE 0: out = f16(elu(agg))            (layer 1 -> h1)
// MODE 1: out = f16(h1 + elu(agg))       (layer 2 -> hsum)
template<int MODE>
__global__ __launch_bounds__(256) void aggregate_cat(const int* __restrict__ row_ptr,
                                                     const int* __restrict__ ssrc,
                                                     const float* __restrict__ cbuf,
                                                     const _Float16* __restrict__ Whb,
                                                     const _Float16* __restrict__ h1,
                                                     _Float16* __restrict__ outv, int N) {
  int half = threadIdx.x >> 7;
  int tt = threadIdx.x & 127;
  int n = blockIdx.x * 2 + half;
  if (n >= N) return;
  int idx = tt * 8;
  int h = idx >> 8;   // F=256: all 8 elems in same head

  float acc[8] = {};
  int beg = row_ptr[n], end = row_ptr[n + 1];
  int k = beg;
  for (; k + 1 < end; k += 2) {
    int s0 = ssrc[k], s1 = ssrc[k + 1];
    float c0 = cbuf[(size_t)k * 4 + h];
    float c1 = cbuf[(size_t)(k + 1) * 4 + h];
    f16x8 w0 = *(const f16x8*)&Whb[(size_t)s0 * 1024 + idx];
    f16x8 w1 = *(const f16x8*)&Whb[(size_t)s1 * 1024 + idx];
#pragma unroll
    for (int j = 0; j < 8; ++j) {
      acc[j] += c0 * (float)w0[j];
      acc[j] += c1 * (float)w1[j];
    }
  }
  if (k < end) {
    int s0 = ssrc[k];
    float c0 = cbuf[(size_t)k * 4 + h];
    f16x8 w0 = *(const f16x8*)&Whb[(size_t)s0 * 1024 + idx];
#pragma unroll
    for (int j = 0; j < 8; ++j) acc[j] += c0 * (float)w0[j];
  }

  size_t o = (size_t)n * 1024 + idx;
  f16x8 r1;
  if (MODE == 1) r1 = *(const f16x8*)&h1[o];
  f16x8 vo;
#pragma unroll
  for (int j = 0; j < 8; ++j) {
    float v = acc[j];
    v = v > 0.f ? v : expm1f(v);
    if (MODE == 1) v += (float)r1[j];
    vo[j] = (_Float16)v;
  }
  *(f16x8*)&outv[o] = vo;
}

// ---------------- aggregate for mean layer (H=6,F=121,SW=728) -> fp32 out ----------------
__global__ __launch_bounds__(256) void aggregate_mean(const int* __restrict__ row_ptr,
                                                      const int* __restrict__ ssrc,
                                                      const float* __restrict__ cbuf,
                                                      const _Float16* __restrict__ Whb,
                                                      float* __restrict__ out, int N) {
  constexpr int H = 6, F = 121, HF = 726, SW = 728;
  int n = blockIdx.x;
  int t = threadIdx.x;
  int idx = t * 4;
  bool active = idx < HF;
  int hj[4];
#pragma unroll
  for (int j = 0; j < 4; ++j) {
    int h = (idx + j) / F;
    hj[j] = h < H ? h : H - 1;
  }
  f32x4 acc = (f32x4){0.f, 0.f, 0.f, 0.f};
  int beg = row_ptr[n], end = row_ptr[n + 1];
  if (active) {
    for (int k = beg; k < end; ++k) {
      int s = ssrc[k];
      const float* c = cbuf + (size_t)k * H;
      f16x4 w = *(const f16x4*)&Whb[(size_t)s * SW + idx];
#pragma unroll
      for (int j = 0; j < 4; ++j)
        acc[j] += c[hj[j]] * (float)w[j];
    }
  }
  __shared__ float buf[SW];
  if (active) {
#pragma unroll
    for (int j = 0; j < 4; ++j)
      if (idx + j < HF) buf[idx + j] = acc[j];
  }
  __syncthreads();
  for (int f = t; f < F; f += 256) {
    float s = 0.f;
#pragma unroll
    for (int h = 0; h < H; ++h) s += buf[h * F + f];
    out[(size_t)n * F + f] = s * (1.0f / H);
  }
}

extern "C" void kernel_launch(void* const* d_in, const int* in_sizes, int n_in,
                              void* d_out, int out_size, void* d_ws, size_t ws_size,
                              hipStream_t stream) {
  const float* x  = (const float*)d_in[0];
  const int* eidx = (const int*)d_in[1];
  const float* W1 = (const float*)d_in[2];
  const float* a1 = (const float*)d_in[3];
  const float* W2 = (const float*)d_in[4];
  const float* a2 = (const float*)d_in[5];
  const float* W3 = (const float*)d_in[6];
  const float* a3 = (const float*)d_in[7];
  float* out = (float*)d_out;

  const int N = NN, E = NE;
  const int* src = eidx;
  const int* dst = eidx + E;

  char* ws = (char*)d_ws;
  size_t off = 0;
  auto alloc = [&](size_t bytes) -> void* {
    void* p = ws + off;
    off += (bytes + 255) & ~(size_t)255;
    return p;
  };
  _Float16* Whf  = (_Float16*)alloc((size_t)N * 1024 * 2);  // Wh f16 (stride 1024 or 728)
  _Float16* h1   = (_Float16*)alloc((size_t)N * 1024 * 2);
  _Float16* hsum = (_Float16*)alloc((size_t)N * 1024 * 2);
  _Float16* xh   = (_Float16*)alloc((size_t)N * 64 * 2);
  _Float16* w1   = (_Float16*)alloc((size_t)1024 * 64 * 2);
  _Float16* w2   = (_Float16*)alloc((size_t)1024 * 1024 * 2);
  _Float16* w3   = (_Float16*)alloc((size_t)768 * 1024 * 2);
  float* cbuf  = (float*)alloc((size_t)E * 6 * 4);
  float* atts  = (float*)alloc((size_t)N * 6 * 4);
  float* attd  = (float*)alloc((size_t)N * 6 * 4);
  int* counts  = (int*)alloc((size_t)N * 4);
  int* row_ptr = (int*)alloc((size_t)(N + 1) * 4);
  int* cursor  = (int*)alloc((size_t)N * 4);
  int* ssrc    = (int*)alloc((size_t)E * 4);

  // ---- prep (weights + x) and CSR ----
  hipMemsetAsync(counts, 0, (size_t)N * 4, stream);
  prep_kernel<<<(SEG0 + SEG1 + SEG2 + SEG3 + 255) / 256, 256, 0, stream>>>(x, W1, W2, W3, xh, w1, w2, w3);
  count_kernel<<<(E + 255) / 256, 256, 0, stream>>>(dst, counts, E);
  scan_kernel<<<1, 1024, 0, stream>>>(counts, row_ptr, cursor, N);
  scatter_kernel<<<(E + 255) / 256, 256, 0, stream>>>(src, dst, cursor, ssrc, E);

  const int RPG = 10;   // ceil(79 row-blocks / 8 XCDs)

  // ---- layer 1 ----
  gemm_f16<<<8 * RPG * 8, 256, 0, stream>>>(xh, w1, Whf, N, 64, 1024, 8);
  att_kernel<4, 256, 1024><<<N, 256, 0, stream>>>(Whf, a1, atts, attd, N);
  edge_softmax_csr<4><<<N, 64, 0, stream>>>(row_ptr, ssrc, atts, attd, cbuf, N);
  aggregate_cat<0><<<(N + 1) / 2, 256, 0, stream>>>(row_ptr, ssrc, cbuf, Whf, nullptr, h1, N);

  // ---- layer 2 (aggregate emits hsum = h1 + elu(agg)) ----
  gemm_f16<<<8 * RPG * 8, 256, 0, stream>>>(h1, w2, Whf, N, 1024, 1024, 8);
  att_kernel<4, 256, 1024><<<N, 256, 0, stream>>>(Whf, a2, atts, attd, N);
  edge_softmax_csr<4><<<N, 64, 0, stream>>>(row_ptr, ssrc, atts, attd, cbuf, N);
  aggregate_cat<1><<<(N + 1) / 2, 256, 0, stream>>>(row_ptr, ssrc, cbuf, Whf, h1, hsum, N);

  // ---- layer 3 (mean over 6 heads) ----
  gemm_f16<<<8 * RPG * 6, 256, 0, stream>>>(hsum, w3, Whf, N, 1024, 728, 6);
  att_kernel<6, 121, 728><<<N, 384, 0, stream>>>(Whf, a3, atts, attd, N);
  edge_softmax_csr<6><<<N, 64, 0, stream>>>(row_ptr, ssrc, atts, attd, cbuf, N);
  aggregate_mean<<<N, 256, 0, stream>>>(row_ptr, ssrc, cbuf, Whf, out, N);
}

// Round 6
// 299.638 us; speedup vs baseline: 5.5439x; 1.0775x over previous
//
#include <hip/hip_runtime.h>
#include <hip/hip_bf16.h>
#include <math.h>

#define NN 10000
#define NE 160000

typedef __attribute__((ext_vector_type(8))) _Float16 f16x8;
typedef __attribute__((ext_vector_type(4))) _Float16 f16x4;
typedef __attribute__((ext_vector_type(4))) float f32x4;

// ---------------- CSR build ----------------
__global__ void count_kernel(const int* __restrict__ dst, int* __restrict__ counts, int E) {
  int e = blockIdx.x * blockDim.x + threadIdx.x;
  if (e < E) atomicAdd(&counts[dst[e]], 1);
}

__global__ __launch_bounds__(1024) void scan_kernel(const int* __restrict__ counts,
                                                    int* __restrict__ row_ptr,
                                                    int* __restrict__ cursor, int N) {
  __shared__ int sums[1024];
  int t = threadIdx.x;
  const int CH = (N + 1023) >> 10;
  int base = t * CH;
  int s = 0;
  for (int i = 0; i < CH; ++i) { int idx = base + i; if (idx < N) s += counts[idx]; }
  sums[t] = s;
  __syncthreads();
  for (int off = 1; off < 1024; off <<= 1) {
    int v = 0;
    if (t >= off) v = sums[t - off];
    __syncthreads();
    if (t >= off) sums[t] += v;
    __syncthreads();
  }
  int run = (t == 0) ? 0 : sums[t - 1];
  for (int i = 0; i < CH; ++i) {
    int idx = base + i;
    if (idx < N) { row_ptr[idx] = run; cursor[idx] = run; run += counts[idx]; }
  }
  if (t == 0) row_ptr[N] = sums[1023];
}

__global__ void scatter_kernel(const int* __restrict__ src, const int* __restrict__ dst,
                               int* __restrict__ cursor, int* __restrict__ ssrc, int E) {
  int e = blockIdx.x * blockDim.x + threadIdx.x;
  if (e < E) {
    int pos = atomicAdd(&cursor[dst[e]], 1);
    ssrc[pos] = src[e];
  }
}

// ---------------- prep: all weight transposes + x conversion to fp16, one kernel ----------------
#define SEG0 (NN * 64)        // x [10000][50] -> xh [10000][64]
#define SEG1 (1024 * 64)      // W1 [50][1024] -> w1 [1024][64]
#define SEG2 (1024 * 1024)    // W2 [1024][1024] -> w2 [1024][1024]
#define SEG3 (768 * 1024)     // W3 [1024][726] -> w3 [768][1024]
__global__ void prep_kernel(const float* __restrict__ x, const float* __restrict__ W1,
                            const float* __restrict__ W2, const float* __restrict__ W3,
                            _Float16* __restrict__ xh, _Float16* __restrict__ w1,
                            _Float16* __restrict__ w2, _Float16* __restrict__ w3) {
  int i = blockIdx.x * blockDim.x + threadIdx.x;
  if (i < SEG0) {
    int m = i >> 6, k = i & 63;
    xh[i] = (_Float16)(k < 50 ? x[m * 50 + k] : 0.f);
  } else if (i < SEG0 + SEG1) {
    int j = i - SEG0;
    int n = j >> 6, k = j & 63;
    w1[j] = (_Float16)(k < 50 ? W1[k * 1024 + n] : 0.f);
  } else if (i < SEG0 + SEG1 + SEG2) {
    int j = i - SEG0 - SEG1;
    int n = j >> 10, k = j & 1023;
    w2[j] = (_Float16)W2[k * 1024 + n];
  } else if (i < SEG0 + SEG1 + SEG2 + SEG3) {
    int j = i - SEG0 - SEG1 - SEG2;
    int n = j >> 10, k = j & 1023;
    w3[j] = (_Float16)(n < 726 ? W3[k * 726 + n] : 0.f);
  }
}

// ---------------- fp16 MFMA GEMM, XCD-swizzled, 128x128 tile, BK=64 ----------------
__global__ __launch_bounds__(256) void gemm_f16(const _Float16* __restrict__ A,
                                                const _Float16* __restrict__ B,
                                                _Float16* __restrict__ C,
                                                int M, int KP, int NcStore, int NC) {
  int flat = blockIdx.x;
  int xcd = flat & 7;
  int slot = flat >> 3;
  int cblk = slot % NC;
  int rblk = (slot / NC) * 8 + xcd;
  const int m0 = rblk * 128;
  if (m0 >= M) return;
  const int n0 = cblk * 128;

  __shared__ _Float16 As[128 * 72];
  __shared__ _Float16 Bs[128 * 72];

  const int t = threadIdx.x;
  const int lane = t & 63;
  const int wid = t >> 6;
  const int wr = wid >> 1;
  const int wc = wid & 1;
  const int row_in = lane & 15;
  const int kgrp = lane >> 4;

  f32x4 acc[4][4];
#pragma unroll
  for (int i = 0; i < 4; ++i)
#pragma unroll
    for (int j = 0; j < 4; ++j) acc[i][j] = (f32x4){0.f, 0.f, 0.f, 0.f};

  for (int k0 = 0; k0 < KP; k0 += 64) {
    if (k0) __syncthreads();
#pragma unroll
    for (int i = 0; i < 4; ++i) {
      int lin = (i * 256 + t) * 8;
      int row = lin >> 6;
      int k = lin & 63;
      int gm = m0 + row;
      if (gm >= M) gm = M - 1;
      *(f16x8*)&As[row * 72 + k] = *(const f16x8*)&A[(size_t)gm * KP + k0 + k];
      *(f16x8*)&Bs[row * 72 + k] = *(const f16x8*)&B[(size_t)(n0 + row) * KP + k0 + k];
    }
    __syncthreads();

#pragma unroll
    for (int ks = 0; ks < 64; ks += 32) {
      f16x8 a[4], b[4];
#pragma unroll
      for (int mi = 0; mi < 4; ++mi)
        a[mi] = *(const f16x8*)&As[(wr * 64 + mi * 16 + row_in) * 72 + ks + kgrp * 8];
#pragma unroll
      for (int ni = 0; ni < 4; ++ni)
        b[ni] = *(const f16x8*)&Bs[(wc * 64 + ni * 16 + row_in) * 72 + ks + kgrp * 8];
#pragma unroll
      for (int mi = 0; mi < 4; ++mi)
#pragma unroll
        for (int ni = 0; ni < 4; ++ni)
          acc[mi][ni] = __builtin_amdgcn_mfma_f32_16x16x32_f16(a[mi], b[ni], acc[mi][ni], 0, 0, 0);
    }
  }

#pragma unroll
  for (int mi = 0; mi < 4; ++mi) {
#pragma unroll
    for (int ni = 0; ni < 4; ++ni) {
      int gn = n0 + wc * 64 + ni * 16 + row_in;
      if (gn >= NcStore) continue;
#pragma unroll
      for (int j = 0; j < 4; ++j) {
        int gm = m0 + wr * 64 + mi * 16 + kgrp * 4 + j;
        if (gm < M) C[(size_t)gm * NcStore + gn] = (_Float16)acc[mi][ni][j];
      }
    }
  }
}

// ---------------- attention scores from fp16 Wh ----------------
template<int H, int F, int SW>
__global__ void att_kernel(const _Float16* __restrict__ Whb, const float* __restrict__ a,
                           float* __restrict__ att_s, float* __restrict__ att_d, int N) {
  int n = blockIdx.x;
  int h = threadIdx.x >> 6;
  int lane = threadIdx.x & 63;
  const _Float16* w = Whb + (size_t)n * SW + h * F;
  const float* as = a + (size_t)h * 2 * F;
  const float* ad = as + F;
  float ss = 0.f, sd = 0.f;
  for (int f = lane; f < F; f += 64) {
    float v = (float)w[f];
    ss += v * as[f];
    sd += v * ad[f];
  }
#pragma unroll
  for (int off = 32; off > 0; off >>= 1) {
    ss += __shfl_down(ss, off);
    sd += __shfl_down(sd, off);
  }
  if (lane == 0) {
    att_s[n * H + h] = ss;
    att_d[n * H + h] = sd;
  }
}

// ---------------- fused CSR edge softmax (normalized coefs) ----------------
template<int H>
__global__ __launch_bounds__(64) void edge_softmax_csr(const int* __restrict__ row_ptr,
                                                       const int* __restrict__ ssrc,
                                                       const float* __restrict__ att_s,
                                                       const float* __restrict__ att_d,
                                                       float* __restrict__ cbuf, int N) {
  int n = blockIdx.x;
  int lane = threadIdx.x;
  int beg = row_ptr[n], end = row_ptr[n + 1];
  float ad[H];
#pragma unroll
  for (int h = 0; h < H; ++h) ad[h] = att_d[n * H + h];

  float m[H];
#pragma unroll
  for (int h = 0; h < H; ++h) m[h] = -INFINITY;
  for (int k = beg + lane; k < end; k += 64) {
    int s = ssrc[k];
#pragma unroll
    for (int h = 0; h < H; ++h) {
      float x = att_s[s * H + h] + ad[h];
      float l = x >= 0.f ? x : 0.2f * x;
      m[h] = fmaxf(m[h], l);
    }
  }
#pragma unroll
  for (int h = 0; h < H; ++h)
#pragma unroll
    for (int off = 32; off > 0; off >>= 1) m[h] = fmaxf(m[h], __shfl_xor(m[h], off));

  float sum[H];
#pragma unroll
  for (int h = 0; h < H; ++h) sum[h] = 0.f;
  for (int k = beg + lane; k < end; k += 64) {
    int s = ssrc[k];
#pragma unroll
    for (int h = 0; h < H; ++h) {
      float x = att_s[s * H + h] + ad[h];
      float l = x >= 0.f ? x : 0.2f * x;
      float ev = __expf(l - m[h]);
      cbuf[(size_t)k * H + h] = ev;
      sum[h] += ev;
    }
  }
#pragma unroll
  for (int h = 0; h < H; ++h) {
#pragma unroll
    for (int off = 32; off > 0; off >>= 1) sum[h] += __shfl_xor(sum[h], off);
    sum[h] = 1.f / (sum[h] + 1e-16f);
  }
  for (int k = beg + lane; k < end; k += 64) {
#pragma unroll
    for (int h = 0; h < H; ++h) cbuf[(size_t)k * H + h] *= sum[h];
  }
}

// ---------------- chunked aggregate for concat layers (H=4,F=256) ----------------
// 8 feature-chunks of 128; chunk = blockIdx&7 -> pinned to one XCD; per-chunk
// gather slice = 10000 x 256B = 2.56 MB -> L2-resident on that XCD.
// 16 nodes/block, 16 threads/node, f16x8 per thread.
// MODE 0: out = f16(elu(agg));  MODE 1: out = f16(h1 + elu(agg))
template<int MODE>
__global__ __launch_bounds__(256) void aggregate_cat_chunk(const int* __restrict__ row_ptr,
                                                           const int* __restrict__ ssrc,
                                                           const float* __restrict__ cbuf,
                                                           const _Float16* __restrict__ Whb,
                                                           const _Float16* __restrict__ h1,
                                                           _Float16* __restrict__ outv, int N) {
  int b = blockIdx.x;
  int chunk = b & 7;                 // -> XCD id (round-robin dispatch)
  int group = b >> 3;
  int n = group * 16 + (threadIdx.x >> 4);
  if (n >= N) return;
  int tt = threadIdx.x & 15;
  int idx = chunk * 128 + tt * 8;
  int h = chunk >> 1;                // F=256: 2 chunks per head

  float acc[8] = {};
  int beg = row_ptr[n], end = row_ptr[n + 1];
  int k = beg;
  for (; k + 1 < end; k += 2) {
    int s0 = ssrc[k], s1 = ssrc[k + 1];
    float c0 = cbuf[(size_t)k * 4 + h];
    float c1 = cbuf[(size_t)(k + 1) * 4 + h];
    f16x8 w0 = *(const f16x8*)&Whb[(size_t)s0 * 1024 + idx];
    f16x8 w1 = *(const f16x8*)&Whb[(size_t)s1 * 1024 + idx];
#pragma unroll
    for (int j = 0; j < 8; ++j) {
      acc[j] += c0 * (float)w0[j];
      acc[j] += c1 * (float)w1[j];
    }
  }
  if (k < end) {
    int s0 = ssrc[k];
    float c0 = cbuf[(size_t)k * 4 + h];
    f16x8 w0 = *(const f16x8*)&Whb[(size_t)s0 * 1024 + idx];
#pragma unroll
    for (int j = 0; j < 8; ++j) acc[j] += c0 * (float)w0[j];
  }

  size_t o = (size_t)n * 1024 + idx;
  f16x8 r1;
  if (MODE == 1) r1 = *(const f16x8*)&h1[o];
  f16x8 vo;
#pragma unroll
  for (int j = 0; j < 8; ++j) {
    float v = acc[j];
    v = v > 0.f ? v : expm1f(v);
    if (MODE == 1) v += (float)r1[j];
    vo[j] = (_Float16)v;
  }
  *(f16x8*)&outv[o] = vo;
}

// ---------------- aggregate for mean layer (H=6,F=121,SW=728) -> fp32 out ----------------
__global__ __launch_bounds__(256) void aggregate_mean(const int* __restrict__ row_ptr,
                                                      const int* __restrict__ ssrc,
                                                      const float* __restrict__ cbuf,
                                                      const _Float16* __restrict__ Whb,
                                                      float* __restrict__ out, int N) {
  constexpr int H = 6, F = 121, HF = 726, SW = 728;
  int n = blockIdx.x;
  int t = threadIdx.x;
  int idx = t * 4;
  bool active = idx < HF;
  int hj[4];
#pragma unroll
  for (int j = 0; j < 4; ++j) {
    int h = (idx + j) / F;
    hj[j] = h < H ? h : H - 1;
  }
  f32x4 acc = (f32x4){0.f, 0.f, 0.f, 0.f};
  int beg = row_ptr[n], end = row_ptr[n + 1];
  if (active) {
    for (int k = beg; k < end; ++k) {
      int s = ssrc[k];
      const float* c = cbuf + (size_t)k * H;
      f16x4 w = *(const f16x4*)&Whb[(size_t)s * SW + idx];
#pragma unroll
      for (int j = 0; j < 4; ++j)
        acc[j] += c[hj[j]] * (float)w[j];
    }
  }
  __shared__ float buf[SW];
  if (active) {
#pragma unroll
    for (int j = 0; j < 4; ++j)
      if (idx + j < HF) buf[idx + j] = acc[j];
  }
  __syncthreads();
  for (int f = t; f < F; f += 256) {
    float s = 0.f;
#pragma unroll
    for (int h = 0; h < H; ++h) s += buf[h * F + f];
    out[(size_t)n * F + f] = s * (1.0f / H);
  }
}

extern "C" void kernel_launch(void* const* d_in, const int* in_sizes, int n_in,
                              void* d_out, int out_size, void* d_ws, size_t ws_size,
                              hipStream_t stream) {
  const float* x  = (const float*)d_in[0];
  const int* eidx = (const int*)d_in[1];
  const float* W1 = (const float*)d_in[2];
  const float* a1 = (const float*)d_in[3];
  const float* W2 = (const float*)d_in[4];
  const float* a2 = (const float*)d_in[5];
  const float* W3 = (const float*)d_in[6];
  const float* a3 = (const float*)d_in[7];
  float* out = (float*)d_out;

  const int N = NN, E = NE;
  const int* src = eidx;
  const int* dst = eidx + E;

  char* ws = (char*)d_ws;
  size_t off = 0;
  auto alloc = [&](size_t bytes) -> void* {
    void* p = ws + off;
    off += (bytes + 255) & ~(size_t)255;
    return p;
  };
  _Float16* Whf  = (_Float16*)alloc((size_t)N * 1024 * 2);
  _Float16* h1   = (_Float16*)alloc((size_t)N * 1024 * 2);
  _Float16* hsum = (_Float16*)alloc((size_t)N * 1024 * 2);
  _Float16* xh   = (_Float16*)alloc((size_t)N * 64 * 2);
  _Float16* w1   = (_Float16*)alloc((size_t)1024 * 64 * 2);
  _Float16* w2   = (_Float16*)alloc((size_t)1024 * 1024 * 2);
  _Float16* w3   = (_Float16*)alloc((size_t)768 * 1024 * 2);
  float* cbuf  = (float*)alloc((size_t)E * 6 * 4);
  float* atts  = (float*)alloc((size_t)N * 6 * 4);
  float* attd  = (float*)alloc((size_t)N * 6 * 4);
  int* counts  = (int*)alloc((size_t)N * 4);
  int* row_ptr = (int*)alloc((size_t)(N + 1) * 4);
  int* cursor  = (int*)alloc((size_t)N * 4);
  int* ssrc    = (int*)alloc((size_t)E * 4);

  // ---- prep (weights + x) and CSR ----
  hipMemsetAsync(counts, 0, (size_t)N * 4, stream);
  prep_kernel<<<(SEG0 + SEG1 + SEG2 + SEG3 + 255) / 256, 256, 0, stream>>>(x, W1, W2, W3, xh, w1, w2, w3);
  count_kernel<<<(E + 255) / 256, 256, 0, stream>>>(dst, counts, E);
  scan_kernel<<<1, 1024, 0, stream>>>(counts, row_ptr, cursor, N);
  scatter_kernel<<<(E + 255) / 256, 256, 0, stream>>>(src, dst, cursor, ssrc, E);

  const int RPG = 10;   // ceil(79 row-blocks / 8 XCDs)
  const int AGG_GRID = 8 * ((N + 15) / 16);   // 8 chunks x node-groups

  // ---- layer 1 ----
  gemm_f16<<<8 * RPG * 8, 256, 0, stream>>>(xh, w1, Whf, N, 64, 1024, 8);
  att_kernel<4, 256, 1024><<<N, 256, 0, stream>>>(Whf, a1, atts, attd, N);
  edge_softmax_csr<4><<<N, 64, 0, stream>>>(row_ptr, ssrc, atts, attd, cbuf, N);
  aggregate_cat_chunk<0><<<AGG_GRID, 256, 0, stream>>>(row_ptr, ssrc, cbuf, Whf, nullptr, h1, N);

  // ---- layer 2 (aggregate emits hsum = h1 + elu(agg)) ----
  gemm_f16<<<8 * RPG * 8, 256, 0, stream>>>(h1, w2, Whf, N, 1024, 1024, 8);
  att_kernel<4, 256, 1024><<<N, 256, 0, stream>>>(Whf, a2, atts, attd, N);
  edge_softmax_csr<4><<<N, 64, 0, stream>>>(row_ptr, ssrc, atts, attd, cbuf, N);
  aggregate_cat_chunk<1><<<AGG_GRID, 256, 0, stream>>>(row_ptr, ssrc, cbuf, Whf, h1, hsum, N);

  // ---- layer 3 (mean over 6 heads) ----
  gemm_f16<<<8 * RPG * 6, 256, 0, stream>>>(hsum, w3, Whf, N, 1024, 728, 6);
  att_kernel<6, 121, 728><<<N, 384, 0, stream>>>(Whf, a3, atts, attd, N);
  edge_softmax_csr<6><<<N, 64, 0, stream>>>(row_ptr, ssrc, atts, attd, cbuf, N);
  aggregate_mean<<<N, 256, 0, stream>>>(row_ptr, ssrc, cbuf, Whf, out, N);
}